// Round 8
// baseline (150.975 us; speedup 1.0000x reference)
//
#include <hip/hip_runtime.h>
#include <hip/hip_bf16.h>
#include <math.h>

#define HW 4096
#define NC 256
#define NB 8
#define NA 5
#define NIT 24
#define SCL 0.0625f

// workspace layout (float offsets).
// Region A (655360 floats) reuse, in stream order:
//   1) k_attnlogF writes full L [sb16][a5][4096] (front 327680)
//   2) k_sinkhorn reads L, writes plan P [sb16][a5][4096] in place
//   3) k_ps consumes P; then k_attn2log writes partials [ct2][b8][i10][4096]
//      (exactly 655360 floats, fills region A)
// OFF_WQK aliases OFF_W2: Wqk lives there from k_stage1 until k_attnlogF
// reads it; k_softmax2 overwrites the region much later.
#define OFF_A     0
#define OFF_PROTO 655360                   // 2*8*256
#define OFF_PS    (OFF_PROTO + 4096 + 20480)
#define OFF_W2    (OFF_PS + 20480)         // 8*10*4096
#define OFF_WQK   OFF_W2                   // 256*256 alias (dead before softmax2)

__device__ inline float frcp(float x) { return __builtin_amdgcn_rcpf(x); }

// ---- DPP wave64 reductions: result valid in lane 63 ----
template<int NV>
__device__ inline void waveSum(float (&v)[NV]) {
    #pragma unroll
    for (int k = 0; k < NV; ++k) {
        float x = v[k]; int t;
        t = __builtin_amdgcn_update_dpp(0, __float_as_int(x), 0x111, 0xf, 0xf, true); x += __int_as_float(t);
        t = __builtin_amdgcn_update_dpp(0, __float_as_int(x), 0x112, 0xf, 0xf, true); x += __int_as_float(t);
        t = __builtin_amdgcn_update_dpp(0, __float_as_int(x), 0x114, 0xf, 0xf, true); x += __int_as_float(t);
        t = __builtin_amdgcn_update_dpp(0, __float_as_int(x), 0x118, 0xf, 0xf, true); x += __int_as_float(t);
        t = __builtin_amdgcn_update_dpp(0, __float_as_int(x), 0x142, 0xf, 0xf, true); x += __int_as_float(t);
        t = __builtin_amdgcn_update_dpp(0, __float_as_int(x), 0x143, 0xf, 0xf, true); x += __int_as_float(t);
        v[k] = x;
    }
}

template<int NV>
__device__ inline void waveMax(float (&v)[NV]) {
    #pragma unroll
    for (int k = 0; k < NV; ++k) {
        float x = v[k]; int t;
        t = __builtin_amdgcn_update_dpp(__float_as_int(x), __float_as_int(x), 0x111, 0xf, 0xf, false); x = fmaxf(x, __int_as_float(t));
        t = __builtin_amdgcn_update_dpp(__float_as_int(x), __float_as_int(x), 0x112, 0xf, 0xf, false); x = fmaxf(x, __int_as_float(t));
        t = __builtin_amdgcn_update_dpp(__float_as_int(x), __float_as_int(x), 0x114, 0xf, 0xf, false); x = fmaxf(x, __int_as_float(t));
        t = __builtin_amdgcn_update_dpp(__float_as_int(x), __float_as_int(x), 0x118, 0xf, 0xf, false); x = fmaxf(x, __int_as_float(t));
        t = __builtin_amdgcn_update_dpp(__float_as_int(x), __float_as_int(x), 0x142, 0xf, 0xf, false); x = fmaxf(x, __int_as_float(t));
        t = __builtin_amdgcn_update_dpp(__float_as_int(x), __float_as_int(x), 0x143, 0xf, 0xf, false); x = fmaxf(x, __int_as_float(t));
        v[k] = x;
    }
}

template<int NV>
__device__ inline void crossSum4(float (&v)[NV], float* buf, int lane, int wid) {
    waveSum<NV>(v);
    if (lane == 63) {
        #pragma unroll
        for (int k = 0; k < NV; ++k) buf[wid * NV + k] = v[k];
    }
    __syncthreads();
    #pragma unroll
    for (int k = 0; k < NV; ++k)
        v[k] = buf[k] + buf[NV + k] + buf[2 * NV + k] + buf[3 * NV + k];
}

template<int NV>
__device__ inline void crossMax4(float (&v)[NV], float* buf, int lane, int wid) {
    waveMax<NV>(v);
    if (lane == 63) {
        #pragma unroll
        for (int k = 0; k < NV; ++k) buf[wid * NV + k] = v[k];
    }
    __syncthreads();
    #pragma unroll
    for (int k = 0; k < NV; ++k)
        v[k] = fmaxf(fmaxf(buf[k], buf[NV + k]), fmaxf(buf[2 * NV + k], buf[3 * NV + k]));
}

// blocks 0..2047: proto for a PAIR of c rows (mask row read once per pair).
// blocks 2048..2303: Wqk = Wq^T @ Wk.
__global__ __launch_bounds__(256) void k_stage1(const float* __restrict__ f1, const float* __restrict__ f2,
                                                const int* __restrict__ m1, const int* __restrict__ m2,
                                                const float* __restrict__ Wq, const float* __restrict__ Wk,
                                                float* __restrict__ ws) {
    __shared__ float buf[12];
    int bid = blockIdx.x, tid = threadIdx.x;
    if (bid < 2048) {
        int lane = tid & 63, wid = tid >> 6;
        int s = bid >> 10, b = (bid >> 7) & 7, cp = bid & 127;
        int c0 = cp * 2;
        const float* f = s ? f2 : f1;
        const int* m = s ? m2 : m1;
        const float4* r0 = (const float4*)(f + ((size_t)b * NC + c0) * HW);
        const float4* r1 = (const float4*)(f + ((size_t)b * NC + c0 + 1) * HW);
        const int4* mb4 = (const int4*)(m + b * HW);
        float v3[3] = {0.f, 0.f, 0.f};   // sum_c0, sum_c1, count
        #pragma unroll
        for (int j = 0; j < 4; ++j) {
            int idx = tid + j * 256;
            float4 a = r0[idx];
            float4 c = r1[idx];
            int4 mm = mb4[idx];
            if (mm.x == 1) { v3[0] += a.x; v3[1] += c.x; v3[2] += 1.f; }
            if (mm.y == 1) { v3[0] += a.y; v3[1] += c.y; v3[2] += 1.f; }
            if (mm.z == 1) { v3[0] += a.z; v3[1] += c.z; v3[2] += 1.f; }
            if (mm.w == 1) { v3[0] += a.w; v3[1] += c.w; v3[2] += 1.f; }
        }
        crossSum4<3>(v3, buf, lane, wid);
        if (tid == 0) {
            float inv = 1.f / (v3[2] + 1e-5f);
            float* p = ws + OFF_PROTO + (s * 8 + b) * NC + c0;
            p[0] = v3[0] * inv;
            p[1] = v3[1] * inv;
        }
    } else {
        int c1 = bid - 2048;
        float acc = 0.f;
        #pragma unroll 8
        for (int cp = 0; cp < NC; ++cp)
            acc += Wq[(size_t)cp * NC + c1] * Wk[(size_t)cp * NC + tid];   // c1 uniform (s_load), tid coalesced
        ws[OFF_WQK + (size_t)c1 * NC + tid] = acc;
    }
}

// phase A: qk[a][cout] = sum_ci (proto+tok)[a][ci] * Wqk[ci][cout]  (cout-parallel, coalesced)
// phase B: L[sb][a][n] = sum_c qk[a][c]*feat[c][n]  (full-c dot, final L)
// grid = 16sb x 16nt = 256 blocks; thread owns 1 n in phase B.
__global__ __launch_bounds__(256) void k_attnlogF(const float* __restrict__ f1, const float* __restrict__ f2,
                                                  const float* __restrict__ tok, float* __restrict__ ws) {
    __shared__ float sp3[NA * NC];
    __shared__ float qk_l[NA * NC];
    int bid = blockIdx.x, tid = threadIdx.x;
    int nt = bid & 15, sb = bid >> 4;
    int s = sb >> 3, b = sb & 7;
    const float* f = s ? f2 : f1;
    const float* proto = ws + OFF_PROTO + sb * NC;
    for (int i = tid; i < NA * NC; i += 256) sp3[i] = proto[i & 255] + tok[i];
    __syncthreads();
    {   // phase A: thread = cout; Wqk[ci][cout] coalesced across threads
        const float* wq = ws + OFF_WQK + tid;
        float a0 = 0, a1 = 0, a2 = 0, a3 = 0, a4 = 0;
        #pragma unroll 8
        for (int ci = 0; ci < NC; ++ci) {
            float w = wq[(size_t)ci * NC];
            a0 += sp3[0 * NC + ci] * w; a1 += sp3[1 * NC + ci] * w; a2 += sp3[2 * NC + ci] * w;
            a3 += sp3[3 * NC + ci] * w; a4 += sp3[4 * NC + ci] * w;
        }
        qk_l[0 * NC + tid] = a0; qk_l[1 * NC + tid] = a1; qk_l[2 * NC + tid] = a2;
        qk_l[3 * NC + tid] = a3; qk_l[4 * NC + tid] = a4;
    }
    __syncthreads();
    // phase B: n = nt*256 + tid
    int n = nt * 256 + tid;
    const float* fb = f + (size_t)b * NC * HW + n;
    float acc[NA] = {};
    #pragma unroll 4
    for (int c = 0; c < NC; ++c) {
        float v = fb[(size_t)c * HW];
        #pragma unroll
        for (int a = 0; a < NA; ++a) acc[a] += qk_l[a * NC + c] * v;
    }
    float* Lb = ws + OFF_A + (size_t)sb * NA * HW;
    #pragma unroll
    for (int a = 0; a < NA; ++a) Lb[a * HW + n] = acc[a];
}

// read L -> masked softmax -> K=exp(2*attn-2)*mask -> NIT iters -> plan P (in place)
__global__ __launch_bounds__(256) void k_sinkhorn(const int* __restrict__ m1, const int* __restrict__ m2,
                                                  float* __restrict__ ws) {
    __shared__ float buf[2][24];
    int sb = blockIdx.x, tid = threadIdx.x;
    int lane = tid & 63, wid = tid >> 6;
    int s = sb >> 3, b = sb & 7;
    const int* m = (s ? m2 : m1) + b * HW;
    const float4* A4 = (const float4*)(ws + OFF_A) + (size_t)sb * NA * 1024;
    const int4* mb4 = (const int4*)m;

    unsigned mbits = 0;
    float K[NA][16];
    #pragma unroll
    for (int j = 0; j < 4; ++j) {
        int idx = tid + j * 256;
        int4 mm = mb4[idx];
        if (mm.x == 1) mbits |= 1u << (4 * j + 0);
        if (mm.y == 1) mbits |= 1u << (4 * j + 1);
        if (mm.z == 1) mbits |= 1u << (4 * j + 2);
        if (mm.w == 1) mbits |= 1u << (4 * j + 3);
        #pragma unroll
        for (int a = 0; a < NA; ++a) {
            float4 l0 = A4[a * 1024 + idx];
            K[a][4 * j + 0] = l0.x; K[a][4 * j + 1] = l0.y;
            K[a][4 * j + 2] = l0.z; K[a][4 * j + 3] = l0.w;
        }
    }
    float r[NA];
    #pragma unroll
    for (int a = 0; a < NA; ++a) {
        float mx = -3.0e38f;
        #pragma unroll
        for (int j = 0; j < 16; ++j)
            if ((mbits >> j) & 1) mx = fmaxf(mx, K[a][j]);
        r[a] = mx;
    }
    crossMax4<NA>(r, buf[0], lane, wid);
    float rs6[6];
    #pragma unroll
    for (int a = 0; a < NA; ++a) {
        float sum = 0.f;
        #pragma unroll
        for (int j = 0; j < 16; ++j) {
            float e = ((mbits >> j) & 1) ? expf(K[a][j] - r[a]) : 0.f;
            K[a][j] = e; sum += e;
        }
        rs6[a] = sum;
    }
    rs6[5] = (float)__popc(mbits);
    crossSum4<6>(rs6, buf[1], lane, wid);
    float inv_cnt = frcp(rs6[5]);
    #pragma unroll
    for (int a = 0; a < NA; ++a) {
        float irs = frcp(rs6[a]);
        #pragma unroll
        for (int j = 0; j < 16; ++j) {
            float attn = K[a][j] * irs;
            K[a][j] = ((mbits >> j) & 1) ? expf(2.f * attn - 2.f) : 0.f;
        }
    }
    float u[NA];
    #pragma unroll
    for (int a = 0; a < NA; ++a) u[a] = 0.2f;
    for (int it = 0; it < NIT; ++it) {
        float part[NA] = {0, 0, 0, 0, 0};
        #pragma unroll
        for (int j = 0; j < 16; ++j) {
            float d = 0.f;
            #pragma unroll
            for (int a = 0; a < NA; ++a) d += K[a][j] * u[a];
            float t = inv_cnt * frcp(fmaxf(d, 1e-30f));
            #pragma unroll
            for (int a = 0; a < NA; ++a) part[a] += K[a][j] * t;
        }
        crossSum4<NA>(part, buf[it & 1], lane, wid);
        #pragma unroll
        for (int a = 0; a < NA; ++a) u[a] = 0.2f * frcp(fmaxf(part[a], 1e-30f));
    }
    float4* Pb4 = (float4*)(ws + OFF_A) + (size_t)sb * NA * 1024;   // overwrite own L
    #pragma unroll
    for (int j4 = 0; j4 < 4; ++j4) {
        int idx = tid + j4 * 256;
        float tcol[4];
        #pragma unroll
        for (int k = 0; k < 4; ++k) {
            int j = 4 * j4 + k;
            float d = 0.f;
            #pragma unroll
            for (int a = 0; a < NA; ++a) d += K[a][j] * u[a];
            tcol[k] = inv_cnt * frcp(fmaxf(d, 1e-30f));
        }
        #pragma unroll
        for (int a = 0; a < NA; ++a) {
            float4 o;
            o.x = u[a] * K[a][4 * j4 + 0] * tcol[0];
            o.y = u[a] * K[a][4 * j4 + 1] * tcol[1];
            o.z = u[a] * K[a][4 * j4 + 2] * tcol[2];
            o.w = u[a] * K[a][4 * j4 + 3] * tcol[3];
            Pb4[a * 1024 + idx] = o;
        }
    }
}

// ps[s][b][a][c] = sum_n P[a][n]*feat[c][n]
__global__ __launch_bounds__(256) void k_ps(const float* __restrict__ f1, const float* __restrict__ f2,
                                            float* __restrict__ ws) {
    __shared__ float buf[20];
    int bid = blockIdx.x, tid = threadIdx.x;
    int lane = tid & 63, wid = tid >> 6;
    int s = bid >> 11, b = (bid >> 8) & 7, c = bid & 255;
    const float* f = s ? f2 : f1;
    int sb = s * 8 + b;
    const float4* fb4 = (const float4*)(f + ((size_t)b * NC + c) * HW);
    const float4* Pb4 = (const float4*)(ws + OFF_A) + (size_t)sb * NA * 1024;
    float acc[NA] = {0, 0, 0, 0, 0};
    #pragma unroll
    for (int j = 0; j < 4; ++j) {
        int idx = tid + j * 256;
        float4 v = fb4[idx];
        #pragma unroll
        for (int a = 0; a < NA; ++a) {
            float4 p = Pb4[a * 1024 + idx];
            acc[a] += p.x * v.x + p.y * v.y + p.z * v.z + p.w * v.w;
        }
    }
    crossSum4<NA>(acc, buf, lane, wid);
    if (tid == 0) {
        float* ps = ws + OFF_PS + sb * NA * NC;
        #pragma unroll
        for (int a = 0; a < NA; ++a) ps[a * NC + c] = acc[a];
    }
}

// mem rows 0..9: proto3 + ps @ Wv^T.  grid = 16sb x 16 cout-tiles = 256 blocks.
__global__ __launch_bounds__(256) void k_outproto(const float* __restrict__ Wv, const float* __restrict__ tok,
                                                  float* __restrict__ ws, float* __restrict__ out) {
    __shared__ float wv_l[16][NC + 1];   // +1 pad: kills 16-way bank conflict
    __shared__ float ps_l[NA * NC];
    __shared__ float part[80][2];
    int bid = blockIdx.x, tid = threadIdx.x;
    int ctile = bid & 15, sb = bid >> 4;
    int s = sb >> 3, b = sb & 7;
    int c0 = ctile * 16;
    const float4* wv4 = (const float4*)(Wv + (size_t)c0 * NC);
    for (int t = tid; t < 1024; t += 256) {
        int r = t >> 6, q = t & 63;
        float4 v = wv4[(size_t)r * 64 + q];
        wv_l[r][4 * q + 0] = v.x; wv_l[r][4 * q + 1] = v.y;
        wv_l[r][4 * q + 2] = v.z; wv_l[r][4 * q + 3] = v.w;
    }
    const float* ps = ws + OFF_PS + sb * NA * NC;
    for (int i = tid; i < NA * NC; i += 256) ps_l[i] = ps[i];
    __syncthreads();
    if (tid < 160) {
        int o = tid >> 1, seg = tid & 1;
        int a = o >> 4, r = o & 15;
        const float* pa = ps_l + a * NC + seg * 128;
        const float* wr = &wv_l[r][seg * 128];
        float d = 0.f;
        #pragma unroll 8
        for (int i = 0; i < 128; ++i) d += pa[i] * wr[i];
        part[o][seg] = d;
    }
    __syncthreads();
    if (tid < 80) {
        int a = tid >> 4, r = tid & 15;
        int c = c0 + r;
        out[(size_t)b * 20 * NC + (s * NA + a) * NC + c] =
            ws[OFF_PROTO + sb * NC + c] + tok[a * NC + c] + part[tid][0] + part[tid][1];
    }
}

// attn2 logit partials, ALL 10 rows per block (qf read once), curr weights via
// wave-uniform global loads (s_load path; no LDS staging).
// grid = 8b x 8nt x 2ct = 128 blocks; thread owns 2 n.
// writes partials [ct2][b8][i10][4096] over region A (P already consumed by k_ps).
__global__ __launch_bounds__(256) void k_attn2log(const float* __restrict__ qf, const float* __restrict__ out,
                                                  float* __restrict__ ws) {
    int bid = blockIdx.x, tid = threadIdx.x;
    int ct = bid & 1, nt = (bid >> 1) & 7, b = bid >> 4;
    const float* cw = out + (size_t)b * 20 * NC + ct * 128;   // block-uniform base
    int h0 = nt * 256 + tid;                                  // float2 index
    const float2* fb2 = (const float2*)(qf + (size_t)b * NC * HW + (size_t)ct * 128 * HW);
    float2 acc[10] = {};
    #pragma unroll 2
    for (int k = 0; k < 128; ++k) {
        float2 v = fb2[(size_t)k * 2048 + h0];
        #pragma unroll
        for (int i = 0; i < 10; ++i) {
            float w = cw[i * NC + k];                         // uniform -> scalar load
            acc[i].x += w * v.x; acc[i].y += w * v.y;
        }
    }
    float2* pp = (float2*)(ws + OFF_A + (size_t)((ct * 8 + b) * 10) * HW);
    #pragma unroll
    for (int i = 0; i < 10; ++i) pp[(size_t)i * 2048 + h0] = acc[i];
}

// sum 2 c-half partials, fg from qp inline, *SCL*fg, softmax, store attn*fg
__global__ __launch_bounds__(256) void k_softmax2(const float* __restrict__ qp, float* __restrict__ ws) {
    __shared__ float buf[2][8];
    int row = blockIdx.x, tid = threadIdx.x;
    int lane = tid & 63, wid = tid >> 6;
    int b = row / 10, i = row - b * 10;
    const float4* pA = (const float4*)(ws + OFF_A) + (size_t)(b * 10 + i) * 1024;          // ct=0
    const float4* pB = (const float4*)(ws + OFF_A) + (size_t)((8 + b) * 10 + i) * 1024;    // ct=1
    const float4* qp0 = (const float4*)(qp + (size_t)b * 2 * HW);
    const float4* qp1 = qp0 + 1024;
    float4 lg[4], fgv[4];
    float mx[1] = {-3.0e38f};
    #pragma unroll
    for (int j = 0; j < 4; ++j) {
        int idx = tid + j * 256;
        float4 a = pA[idx], c = pB[idx];
        float4 p0 = qp0[idx], p1 = qp1[idx];
        float4 fg;
        fg.x = 1.f / (1.f + expf(p0.x - p1.x));
        fg.y = 1.f / (1.f + expf(p0.y - p1.y));
        fg.z = 1.f / (1.f + expf(p0.z - p1.z));
        fg.w = 1.f / (1.f + expf(p0.w - p1.w));
        fg.x = fg.x > 0.7f ? 1.f : (fg.x < 0.3f ? 0.f : fg.x);
        fg.y = fg.y > 0.7f ? 1.f : (fg.y < 0.3f ? 0.f : fg.y);
        fg.z = fg.z > 0.7f ? 1.f : (fg.z < 0.3f ? 0.f : fg.z);
        fg.w = fg.w > 0.7f ? 1.f : (fg.w < 0.3f ? 0.f : fg.w);
        fgv[j] = fg;
        lg[j].x = (a.x + c.x) * SCL * fg.x;
        lg[j].y = (a.y + c.y) * SCL * fg.y;
        lg[j].z = (a.z + c.z) * SCL * fg.z;
        lg[j].w = (a.w + c.w) * SCL * fg.w;
        mx[0] = fmaxf(mx[0], fmaxf(fmaxf(lg[j].x, lg[j].y), fmaxf(lg[j].z, lg[j].w)));
    }
    crossMax4<1>(mx, buf[0], lane, wid);
    float sum[1] = {0.f};
    #pragma unroll
    for (int j = 0; j < 4; ++j) {
        lg[j].x = expf(lg[j].x - mx[0]); lg[j].y = expf(lg[j].y - mx[0]);
        lg[j].z = expf(lg[j].z - mx[0]); lg[j].w = expf(lg[j].w - mx[0]);
        sum[0] += lg[j].x + lg[j].y + lg[j].z + lg[j].w;
    }
    crossSum4<1>(sum, buf[1], lane, wid);
    float inv = frcp(sum[0]);
    float4* w24 = (float4*)(ws + OFF_W2) + (size_t)row * 1024;
    #pragma unroll
    for (int j = 0; j < 4; ++j) {
        int idx = tid + j * 256;
        float4 o;
        o.x = lg[j].x * inv * fgv[j].x;
        o.y = lg[j].y * inv * fgv[j].y;
        o.z = lg[j].z * inv * fgv[j].z;
        o.w = lg[j].w * inv * fgv[j].w;
        w24[idx] = o;
    }
}

// mem rows 10..19 = rows 0..9 + attn@qfm ; fused curr_prototype mean.
// grid = 8b x 64 column-groups (4 c each); all reg-array indexing static.
__global__ __launch_bounds__(256) void k_apply2(const float* __restrict__ qf, float* __restrict__ ws,
                                                float* __restrict__ out) {
    __shared__ float buf[4 * 40];
    int bid = blockIdx.x, tid = threadIdx.x;
    int lane = tid & 63, wid = tid >> 6;
    int b = bid >> 6, cg = bid & 63;
    int c0 = cg * 4;
    const float4* qf4 = (const float4*)(qf + (size_t)b * NC * HW);
    const float4* w24 = (const float4*)(ws + OFF_W2) + (size_t)b * 10 * 1024;
    float acc[40] = {};
    #pragma unroll
    for (int j = 0; j < 4; ++j) {
        int idx = tid + j * 256;
        float4 wv[10];
        #pragma unroll
        for (int i = 0; i < 10; ++i) wv[i] = w24[i * 1024 + idx];
        #pragma unroll
        for (int cc = 0; cc < 4; ++cc) {
            float4 v = qf4[(size_t)(c0 + cc) * 1024 + idx];
            #pragma unroll
            for (int i = 0; i < 10; ++i)
                acc[cc * 10 + i] += wv[i].x * v.x + wv[i].y * v.y + wv[i].z * v.z + wv[i].w * v.w;
        }
    }
    waveSum<40>(acc);
    if (lane == 63) {
        #pragma unroll
        for (int k = 0; k < 40; ++k) buf[wid * 40 + k] = acc[k];
    }
    __syncthreads();
    if (tid == 0) {
        float* ob = out + (size_t)b * 20 * NC;
        #pragma unroll
        for (int cc = 0; cc < 4; ++cc) {
            float s = 0.f;
            #pragma unroll
            for (int i = 0; i < 10; ++i) {
                float d = buf[cc * 10 + i] + buf[40 + cc * 10 + i]
                        + buf[80 + cc * 10 + i] + buf[120 + cc * 10 + i];
                float base = ob[i * NC + c0 + cc];
                float r = base + d;
                ob[(10 + i) * NC + c0 + cc] = r;
                s += base + r;
            }
            out[40960 + b * NC + c0 + cc] = s * 0.05f;
        }
    }
}

extern "C" void kernel_launch(void* const* d_in, const int* in_sizes, int n_in,
                              void* d_out, int out_size, void* d_ws, size_t ws_size,
                              hipStream_t stream) {
    const float* f1  = (const float*)d_in[0];
    const float* f2  = (const float*)d_in[1];
    const int*   m1  = (const int*)d_in[2];
    const int*   m2  = (const int*)d_in[3];
    const float* qf  = (const float*)d_in[4];
    const float* qp  = (const float*)d_in[5];
    const float* Wq  = (const float*)d_in[6];
    const float* Wk  = (const float*)d_in[7];
    const float* Wv  = (const float*)d_in[8];
    const float* tok = (const float*)d_in[9];
    float* out = (float*)d_out;
    float* ws  = (float*)d_ws;

    k_stage1<<<2304, 256, 0, stream>>>(f1, f2, m1, m2, Wq, Wk, ws);
    k_attnlogF<<<256, 256, 0, stream>>>(f1, f2, tok, ws);
    k_sinkhorn<<<16, 256, 0, stream>>>(m1, m2, ws);
    k_ps<<<4096, 256, 0, stream>>>(f1, f2, ws);
    k_outproto<<<256, 256, 0, stream>>>(Wv, tok, ws, out);
    k_attn2log<<<128, 256, 0, stream>>>(qf, out, ws);
    k_softmax2<<<80, 256, 0, stream>>>(qp, ws);
    k_apply2<<<512, 256, 0, stream>>>(qf, ws, out);
}

// Round 9
// 149.402 us; speedup vs baseline: 1.0105x; 1.0105x over previous
//
#include <hip/hip_runtime.h>
#include <hip/hip_bf16.h>
#include <math.h>

#define HW 4096
#define NC 256
#define NB 8
#define NA 5
#define NIT 24
#define SCL 0.0625f

// workspace layout (float offsets).
// Region A (655360 floats) reuse, in stream order:
//   1) k_attnlogF writes full L [sb16][a5][4096] (front 327680)
//   2) k_sinkhorn reads L, writes plan P [sb16][a5][4096] in place
//   3) k_ps consumes P; then k_attn2log writes partials [ct2][ig2][b8][ii5][4096]
// OFF_WQK aliases OFF_W2: Wqk lives there from k_stage1 until k_attnlogF
// reads it; k_softmax2 overwrites the region much later.
#define OFF_A     0
#define OFF_PROTO 655360                   // 2*8*256
#define OFF_PS    (OFF_PROTO + 4096 + 20480)
#define OFF_W2    (OFF_PS + 20480)         // 8*10*4096
#define OFF_WQK   OFF_W2                   // 256*256 alias (dead before softmax2)

__device__ inline float frcp(float x) { return __builtin_amdgcn_rcpf(x); }

// ---- DPP wave64 reductions: result valid in lane 63 ----
template<int NV>
__device__ inline void waveSum(float (&v)[NV]) {
    #pragma unroll
    for (int k = 0; k < NV; ++k) {
        float x = v[k]; int t;
        t = __builtin_amdgcn_update_dpp(0, __float_as_int(x), 0x111, 0xf, 0xf, true); x += __int_as_float(t);
        t = __builtin_amdgcn_update_dpp(0, __float_as_int(x), 0x112, 0xf, 0xf, true); x += __int_as_float(t);
        t = __builtin_amdgcn_update_dpp(0, __float_as_int(x), 0x114, 0xf, 0xf, true); x += __int_as_float(t);
        t = __builtin_amdgcn_update_dpp(0, __float_as_int(x), 0x118, 0xf, 0xf, true); x += __int_as_float(t);
        t = __builtin_amdgcn_update_dpp(0, __float_as_int(x), 0x142, 0xf, 0xf, true); x += __int_as_float(t);
        t = __builtin_amdgcn_update_dpp(0, __float_as_int(x), 0x143, 0xf, 0xf, true); x += __int_as_float(t);
        v[k] = x;
    }
}

template<int NV>
__device__ inline void waveMax(float (&v)[NV]) {
    #pragma unroll
    for (int k = 0; k < NV; ++k) {
        float x = v[k]; int t;
        t = __builtin_amdgcn_update_dpp(__float_as_int(x), __float_as_int(x), 0x111, 0xf, 0xf, false); x = fmaxf(x, __int_as_float(t));
        t = __builtin_amdgcn_update_dpp(__float_as_int(x), __float_as_int(x), 0x112, 0xf, 0xf, false); x = fmaxf(x, __int_as_float(t));
        t = __builtin_amdgcn_update_dpp(__float_as_int(x), __float_as_int(x), 0x114, 0xf, 0xf, false); x = fmaxf(x, __int_as_float(t));
        t = __builtin_amdgcn_update_dpp(__float_as_int(x), __float_as_int(x), 0x118, 0xf, 0xf, false); x = fmaxf(x, __int_as_float(t));
        t = __builtin_amdgcn_update_dpp(__float_as_int(x), __float_as_int(x), 0x142, 0xf, 0xf, false); x = fmaxf(x, __int_as_float(t));
        t = __builtin_amdgcn_update_dpp(__float_as_int(x), __float_as_int(x), 0x143, 0xf, 0xf, false); x = fmaxf(x, __int_as_float(t));
        v[k] = x;
    }
}

template<int NV>
__device__ inline void crossSum4(float (&v)[NV], float* buf, int lane, int wid) {
    waveSum<NV>(v);
    if (lane == 63) {
        #pragma unroll
        for (int k = 0; k < NV; ++k) buf[wid * NV + k] = v[k];
    }
    __syncthreads();
    #pragma unroll
    for (int k = 0; k < NV; ++k)
        v[k] = buf[k] + buf[NV + k] + buf[2 * NV + k] + buf[3 * NV + k];
}

template<int NV>
__device__ inline void crossMax4(float (&v)[NV], float* buf, int lane, int wid) {
    waveMax<NV>(v);
    if (lane == 63) {
        #pragma unroll
        for (int k = 0; k < NV; ++k) buf[wid * NV + k] = v[k];
    }
    __syncthreads();
    #pragma unroll
    for (int k = 0; k < NV; ++k)
        v[k] = fmaxf(fmaxf(buf[k], buf[NV + k]), fmaxf(buf[2 * NV + k], buf[3 * NV + k]));
}

// blocks 0..2047: proto for a PAIR of c rows (mask row read once per pair).
// blocks 2048..2303: Wqk = Wq^T @ Wk.
__global__ __launch_bounds__(256) void k_stage1(const float* __restrict__ f1, const float* __restrict__ f2,
                                                const int* __restrict__ m1, const int* __restrict__ m2,
                                                const float* __restrict__ Wq, const float* __restrict__ Wk,
                                                float* __restrict__ ws) {
    __shared__ float buf[12];
    int bid = blockIdx.x, tid = threadIdx.x;
    if (bid < 2048) {
        int lane = tid & 63, wid = tid >> 6;
        int s = bid >> 10, b = (bid >> 7) & 7, cp = bid & 127;
        int c0 = cp * 2;
        const float* f = s ? f2 : f1;
        const int* m = s ? m2 : m1;
        const float4* r0 = (const float4*)(f + ((size_t)b * NC + c0) * HW);
        const float4* r1 = (const float4*)(f + ((size_t)b * NC + c0 + 1) * HW);
        const int4* mb4 = (const int4*)(m + b * HW);
        float v3[3] = {0.f, 0.f, 0.f};   // sum_c0, sum_c1, count
        #pragma unroll
        for (int j = 0; j < 4; ++j) {
            int idx = tid + j * 256;
            float4 a = r0[idx];
            float4 c = r1[idx];
            int4 mm = mb4[idx];
            if (mm.x == 1) { v3[0] += a.x; v3[1] += c.x; v3[2] += 1.f; }
            if (mm.y == 1) { v3[0] += a.y; v3[1] += c.y; v3[2] += 1.f; }
            if (mm.z == 1) { v3[0] += a.z; v3[1] += c.z; v3[2] += 1.f; }
            if (mm.w == 1) { v3[0] += a.w; v3[1] += c.w; v3[2] += 1.f; }
        }
        crossSum4<3>(v3, buf, lane, wid);
        if (tid == 0) {
            float inv = 1.f / (v3[2] + 1e-5f);
            float* p = ws + OFF_PROTO + (s * 8 + b) * NC + c0;
            p[0] = v3[0] * inv;
            p[1] = v3[1] * inv;
        }
    } else {
        int c1 = bid - 2048;
        float acc = 0.f;
        #pragma unroll 8
        for (int cp = 0; cp < NC; ++cp)
            acc += Wq[(size_t)cp * NC + c1] * Wk[(size_t)cp * NC + tid];   // c1 uniform (s_load), tid coalesced
        ws[OFF_WQK + (size_t)c1 * NC + tid] = acc;
    }
}

// phase A: qk[a][cout] = sum_ci (proto+tok)[a][ci] * Wqk[ci][cout]  (cout-parallel, coalesced)
// phase B: L[sb][a][n] = sum_c qk[a][c]*feat[c][n]  (full-c dot, final L)
// grid = 16sb x 16nt = 256 blocks; thread owns 1 n in phase B.
__global__ __launch_bounds__(256) void k_attnlogF(const float* __restrict__ f1, const float* __restrict__ f2,
                                                  const float* __restrict__ tok, float* __restrict__ ws) {
    __shared__ float sp3[NA * NC];
    __shared__ float qk_l[NA * NC];
    int bid = blockIdx.x, tid = threadIdx.x;
    int nt = bid & 15, sb = bid >> 4;
    int s = sb >> 3, b = sb & 7;
    const float* f = s ? f2 : f1;
    const float* proto = ws + OFF_PROTO + sb * NC;
    for (int i = tid; i < NA * NC; i += 256) sp3[i] = proto[i & 255] + tok[i];
    __syncthreads();
    {   // phase A: thread = cout; Wqk[ci][cout] coalesced across threads
        const float* wq = ws + OFF_WQK + tid;
        float a0 = 0, a1 = 0, a2 = 0, a3 = 0, a4 = 0;
        #pragma unroll 8
        for (int ci = 0; ci < NC; ++ci) {
            float w = wq[(size_t)ci * NC];
            a0 += sp3[0 * NC + ci] * w; a1 += sp3[1 * NC + ci] * w; a2 += sp3[2 * NC + ci] * w;
            a3 += sp3[3 * NC + ci] * w; a4 += sp3[4 * NC + ci] * w;
        }
        qk_l[0 * NC + tid] = a0; qk_l[1 * NC + tid] = a1; qk_l[2 * NC + tid] = a2;
        qk_l[3 * NC + tid] = a3; qk_l[4 * NC + tid] = a4;
    }
    __syncthreads();
    // phase B: n = nt*256 + tid
    int n = nt * 256 + tid;
    const float* fb = f + (size_t)b * NC * HW + n;
    float acc[NA] = {};
    #pragma unroll 4
    for (int c = 0; c < NC; ++c) {
        float v = fb[(size_t)c * HW];
        #pragma unroll
        for (int a = 0; a < NA; ++a) acc[a] += qk_l[a * NC + c] * v;
    }
    float* Lb = ws + OFF_A + (size_t)sb * NA * HW;
    #pragma unroll
    for (int a = 0; a < NA; ++a) Lb[a * HW + n] = acc[a];
}

// read L -> masked softmax -> K=exp(2*attn-2)*mask -> NIT iters -> plan P (in place)
__global__ __launch_bounds__(256) void k_sinkhorn(const int* __restrict__ m1, const int* __restrict__ m2,
                                                  float* __restrict__ ws) {
    __shared__ float buf[2][24];
    int sb = blockIdx.x, tid = threadIdx.x;
    int lane = tid & 63, wid = tid >> 6;
    int s = sb >> 3, b = sb & 7;
    const int* m = (s ? m2 : m1) + b * HW;
    const float4* A4 = (const float4*)(ws + OFF_A) + (size_t)sb * NA * 1024;
    const int4* mb4 = (const int4*)m;

    unsigned mbits = 0;
    float K[NA][16];
    #pragma unroll
    for (int j = 0; j < 4; ++j) {
        int idx = tid + j * 256;
        int4 mm = mb4[idx];
        if (mm.x == 1) mbits |= 1u << (4 * j + 0);
        if (mm.y == 1) mbits |= 1u << (4 * j + 1);
        if (mm.z == 1) mbits |= 1u << (4 * j + 2);
        if (mm.w == 1) mbits |= 1u << (4 * j + 3);
        #pragma unroll
        for (int a = 0; a < NA; ++a) {
            float4 l0 = A4[a * 1024 + idx];
            K[a][4 * j + 0] = l0.x; K[a][4 * j + 1] = l0.y;
            K[a][4 * j + 2] = l0.z; K[a][4 * j + 3] = l0.w;
        }
    }
    float r[NA];
    #pragma unroll
    for (int a = 0; a < NA; ++a) {
        float mx = -3.0e38f;
        #pragma unroll
        for (int j = 0; j < 16; ++j)
            if ((mbits >> j) & 1) mx = fmaxf(mx, K[a][j]);
        r[a] = mx;
    }
    crossMax4<NA>(r, buf[0], lane, wid);
    float rs6[6];
    #pragma unroll
    for (int a = 0; a < NA; ++a) {
        float sum = 0.f;
        #pragma unroll
        for (int j = 0; j < 16; ++j) {
            float e = ((mbits >> j) & 1) ? expf(K[a][j] - r[a]) : 0.f;
            K[a][j] = e; sum += e;
        }
        rs6[a] = sum;
    }
    rs6[5] = (float)__popc(mbits);
    crossSum4<6>(rs6, buf[1], lane, wid);
    float inv_cnt = frcp(rs6[5]);
    #pragma unroll
    for (int a = 0; a < NA; ++a) {
        float irs = frcp(rs6[a]);
        #pragma unroll
        for (int j = 0; j < 16; ++j) {
            float attn = K[a][j] * irs;
            K[a][j] = ((mbits >> j) & 1) ? expf(2.f * attn - 2.f) : 0.f;
        }
    }
    float u[NA];
    #pragma unroll
    for (int a = 0; a < NA; ++a) u[a] = 0.2f;
    for (int it = 0; it < NIT; ++it) {
        float part[NA] = {0, 0, 0, 0, 0};
        #pragma unroll
        for (int j = 0; j < 16; ++j) {
            float d = 0.f;
            #pragma unroll
            for (int a = 0; a < NA; ++a) d += K[a][j] * u[a];
            float t = inv_cnt * frcp(fmaxf(d, 1e-30f));
            #pragma unroll
            for (int a = 0; a < NA; ++a) part[a] += K[a][j] * t;
        }
        crossSum4<NA>(part, buf[it & 1], lane, wid);
        #pragma unroll
        for (int a = 0; a < NA; ++a) u[a] = 0.2f * frcp(fmaxf(part[a], 1e-30f));
    }
    float4* Pb4 = (float4*)(ws + OFF_A) + (size_t)sb * NA * 1024;   // overwrite own L
    #pragma unroll
    for (int j4 = 0; j4 < 4; ++j4) {
        int idx = tid + j4 * 256;
        float tcol[4];
        #pragma unroll
        for (int k = 0; k < 4; ++k) {
            int j = 4 * j4 + k;
            float d = 0.f;
            #pragma unroll
            for (int a = 0; a < NA; ++a) d += K[a][j] * u[a];
            tcol[k] = inv_cnt * frcp(fmaxf(d, 1e-30f));
        }
        #pragma unroll
        for (int a = 0; a < NA; ++a) {
            float4 o;
            o.x = u[a] * K[a][4 * j4 + 0] * tcol[0];
            o.y = u[a] * K[a][4 * j4 + 1] * tcol[1];
            o.z = u[a] * K[a][4 * j4 + 2] * tcol[2];
            o.w = u[a] * K[a][4 * j4 + 3] * tcol[3];
            Pb4[a * 1024 + idx] = o;
        }
    }
}

// ps[s][b][a][c] = sum_n P[a][n]*feat[c][n]
__global__ __launch_bounds__(256) void k_ps(const float* __restrict__ f1, const float* __restrict__ f2,
                                            float* __restrict__ ws) {
    __shared__ float buf[20];
    int bid = blockIdx.x, tid = threadIdx.x;
    int lane = tid & 63, wid = tid >> 6;
    int s = bid >> 11, b = (bid >> 8) & 7, c = bid & 255;
    const float* f = s ? f2 : f1;
    int sb = s * 8 + b;
    const float4* fb4 = (const float4*)(f + ((size_t)b * NC + c) * HW);
    const float4* Pb4 = (const float4*)(ws + OFF_A) + (size_t)sb * NA * 1024;
    float acc[NA] = {0, 0, 0, 0, 0};
    #pragma unroll
    for (int j = 0; j < 4; ++j) {
        int idx = tid + j * 256;
        float4 v = fb4[idx];
        #pragma unroll
        for (int a = 0; a < NA; ++a) {
            float4 p = Pb4[a * 1024 + idx];
            acc[a] += p.x * v.x + p.y * v.y + p.z * v.z + p.w * v.w;
        }
    }
    crossSum4<NA>(acc, buf, lane, wid);
    if (tid == 0) {
        float* ps = ws + OFF_PS + sb * NA * NC;
        #pragma unroll
        for (int a = 0; a < NA; ++a) ps[a * NC + c] = acc[a];
    }
}

// mem rows 0..9: proto3 + ps @ Wv^T.  grid = 16sb x 16 cout-tiles = 256 blocks.
__global__ __launch_bounds__(256) void k_outproto(const float* __restrict__ Wv, const float* __restrict__ tok,
                                                  float* __restrict__ ws, float* __restrict__ out) {
    __shared__ float wv_l[16][NC + 1];   // +1 pad: kills 16-way bank conflict
    __shared__ float ps_l[NA * NC];
    __shared__ float part[80][2];
    int bid = blockIdx.x, tid = threadIdx.x;
    int ctile = bid & 15, sb = bid >> 4;
    int s = sb >> 3, b = sb & 7;
    int c0 = ctile * 16;
    const float4* wv4 = (const float4*)(Wv + (size_t)c0 * NC);
    for (int t = tid; t < 1024; t += 256) {
        int r = t >> 6, q = t & 63;
        float4 v = wv4[(size_t)r * 64 + q];
        wv_l[r][4 * q + 0] = v.x; wv_l[r][4 * q + 1] = v.y;
        wv_l[r][4 * q + 2] = v.z; wv_l[r][4 * q + 3] = v.w;
    }
    const float* ps = ws + OFF_PS + sb * NA * NC;
    for (int i = tid; i < NA * NC; i += 256) ps_l[i] = ps[i];
    __syncthreads();
    if (tid < 160) {
        int o = tid >> 1, seg = tid & 1;
        int a = o >> 4, r = o & 15;
        const float* pa = ps_l + a * NC + seg * 128;
        const float* wr = &wv_l[r][seg * 128];
        float d = 0.f;
        #pragma unroll 8
        for (int i = 0; i < 128; ++i) d += pa[i] * wr[i];
        part[o][seg] = d;
    }
    __syncthreads();
    if (tid < 80) {
        int a = tid >> 4, r = tid & 15;
        int c = c0 + r;
        out[(size_t)b * 20 * NC + (s * NA + a) * NC + c] =
            ws[OFF_PROTO + sb * NC + c] + tok[a * NC + c] + part[tid][0] + part[tid][1];
    }
}

// attn2 logit partials: part2[ct][ig][b][ii][n] = sum_{c in ct-half} curr[ig*5+ii][c]*qf[c][n]
// grid = 8b x 8nt x 2ct x 2ig = 256 blocks; thread owns 2 n.
// LDS-staged weights read as broadcast ds_read_b128 (4 k per read).
__global__ __launch_bounds__(256) void k_attn2log(const float* __restrict__ qf, const float* __restrict__ out,
                                                  float* __restrict__ ws) {
    __shared__ float sc_l[NA * 128];
    int bid = blockIdx.x, tid = threadIdx.x;
    int ig = bid & 1, ct = (bid >> 1) & 1, nt = (bid >> 2) & 7, b = bid >> 5;
    const float* cb = out + (size_t)b * 20 * NC + ig * NA * NC + ct * 128;
    for (int i = tid; i < NA * 128; i += 256) sc_l[i] = cb[(i >> 7) * NC + (i & 127)];
    __syncthreads();
    int h0 = nt * 256 + tid;   // float2 index
    const float2* fb2 = (const float2*)(qf + (size_t)b * NC * HW + (size_t)ct * 128 * HW);
    const float4* sc4 = (const float4*)sc_l;   // [5][32]
    float2 acc[NA] = {};
    #pragma unroll 2
    for (int k4 = 0; k4 < 32; ++k4) {
        float4 w0 = sc4[0 * 32 + k4], w1 = sc4[1 * 32 + k4], w2 = sc4[2 * 32 + k4],
               w3 = sc4[3 * 32 + k4], w4 = sc4[4 * 32 + k4];
        float2 v0 = fb2[(size_t)(4 * k4 + 0) * 2048 + h0];
        float2 v1 = fb2[(size_t)(4 * k4 + 1) * 2048 + h0];
        float2 v2 = fb2[(size_t)(4 * k4 + 2) * 2048 + h0];
        float2 v3 = fb2[(size_t)(4 * k4 + 3) * 2048 + h0];
        acc[0].x += w0.x * v0.x + w0.y * v1.x + w0.z * v2.x + w0.w * v3.x;
        acc[0].y += w0.x * v0.y + w0.y * v1.y + w0.z * v2.y + w0.w * v3.y;
        acc[1].x += w1.x * v0.x + w1.y * v1.x + w1.z * v2.x + w1.w * v3.x;
        acc[1].y += w1.x * v0.y + w1.y * v1.y + w1.z * v2.y + w1.w * v3.y;
        acc[2].x += w2.x * v0.x + w2.y * v1.x + w2.z * v2.x + w2.w * v3.x;
        acc[2].y += w2.x * v0.y + w2.y * v1.y + w2.z * v2.y + w2.w * v3.y;
        acc[3].x += w3.x * v0.x + w3.y * v1.x + w3.z * v2.x + w3.w * v3.x;
        acc[3].y += w3.x * v0.y + w3.y * v1.y + w3.z * v2.y + w3.w * v3.y;
        acc[4].x += w4.x * v0.x + w4.y * v1.x + w4.z * v2.x + w4.w * v3.x;
        acc[4].y += w4.x * v0.y + w4.y * v1.y + w4.z * v2.y + w4.w * v3.y;
    }
    float2* pp = (float2*)(ws + OFF_A + (size_t)(((ct * 2 + ig) * 8 + b) * NA) * HW);
    #pragma unroll
    for (int ii = 0; ii < NA; ++ii) pp[ii * 2048 + h0] = acc[ii];
}

// sum 2 c-half partials, fg from qp inline, *SCL*fg, softmax, store attn*fg
__global__ __launch_bounds__(256) void k_softmax2(const float* __restrict__ qp, float* __restrict__ ws) {
    __shared__ float buf[2][8];
    int row = blockIdx.x, tid = threadIdx.x;
    int lane = tid & 63, wid = tid >> 6;
    int b = row / 10, i = row - b * 10;
    int ig = i / NA, ii = i - ig * NA;
    const float4* pA = (const float4*)(ws + OFF_A) + (size_t)((ig * 8 + b) * NA + ii) * 1024;
    const float4* pB = (const float4*)(ws + OFF_A) + (size_t)(((2 + ig) * 8 + b) * NA + ii) * 1024;
    const float4* qp0 = (const float4*)(qp + (size_t)b * 2 * HW);
    const float4* qp1 = qp0 + 1024;
    float4 lg[4], fgv[4];
    float mx[1] = {-3.0e38f};
    #pragma unroll
    for (int j = 0; j < 4; ++j) {
        int idx = tid + j * 256;
        float4 a = pA[idx], c = pB[idx];
        float4 p0 = qp0[idx], p1 = qp1[idx];
        float4 fg;
        fg.x = 1.f / (1.f + expf(p0.x - p1.x));
        fg.y = 1.f / (1.f + expf(p0.y - p1.y));
        fg.z = 1.f / (1.f + expf(p0.z - p1.z));
        fg.w = 1.f / (1.f + expf(p0.w - p1.w));
        fg.x = fg.x > 0.7f ? 1.f : (fg.x < 0.3f ? 0.f : fg.x);
        fg.y = fg.y > 0.7f ? 1.f : (fg.y < 0.3f ? 0.f : fg.y);
        fg.z = fg.z > 0.7f ? 1.f : (fg.z < 0.3f ? 0.f : fg.z);
        fg.w = fg.w > 0.7f ? 1.f : (fg.w < 0.3f ? 0.f : fg.w);
        fgv[j] = fg;
        lg[j].x = (a.x + c.x) * SCL * fg.x;
        lg[j].y = (a.y + c.y) * SCL * fg.y;
        lg[j].z = (a.z + c.z) * SCL * fg.z;
        lg[j].w = (a.w + c.w) * SCL * fg.w;
        mx[0] = fmaxf(mx[0], fmaxf(fmaxf(lg[j].x, lg[j].y), fmaxf(lg[j].z, lg[j].w)));
    }
    crossMax4<1>(mx, buf[0], lane, wid);
    float sum[1] = {0.f};
    #pragma unroll
    for (int j = 0; j < 4; ++j) {
        lg[j].x = expf(lg[j].x - mx[0]); lg[j].y = expf(lg[j].y - mx[0]);
        lg[j].z = expf(lg[j].z - mx[0]); lg[j].w = expf(lg[j].w - mx[0]);
        sum[0] += lg[j].x + lg[j].y + lg[j].z + lg[j].w;
    }
    crossSum4<1>(sum, buf[1], lane, wid);
    float inv = frcp(sum[0]);
    float4* w24 = (float4*)(ws + OFF_W2) + (size_t)row * 1024;
    #pragma unroll
    for (int j = 0; j < 4; ++j) {
        int idx = tid + j * 256;
        float4 o;
        o.x = lg[j].x * inv * fgv[j].x;
        o.y = lg[j].y * inv * fgv[j].y;
        o.z = lg[j].z * inv * fgv[j].z;
        o.w = lg[j].w * inv * fgv[j].w;
        w24[idx] = o;
    }
}

// mem rows 10..19 = rows 0..9 + attn@qfm ; fused curr_prototype mean.
// grid = 8b x 64 column-groups (4 c each); all reg-array indexing static.
__global__ __launch_bounds__(256) void k_apply2(const float* __restrict__ qf, float* __restrict__ ws,
                                                float* __restrict__ out) {
    __shared__ float buf[4 * 40];
    int bid = blockIdx.x, tid = threadIdx.x;
    int lane = tid & 63, wid = tid >> 6;
    int b = bid >> 6, cg = bid & 63;
    int c0 = cg * 4;
    const float4* qf4 = (const float4*)(qf + (size_t)b * NC * HW);
    const float4* w24 = (const float4*)(ws + OFF_W2) + (size_t)b * 10 * 1024;
    float acc[40] = {};
    #pragma unroll
    for (int j = 0; j < 4; ++j) {
        int idx = tid + j * 256;
        float4 wv[10];
        #pragma unroll
        for (int i = 0; i < 10; ++i) wv[i] = w24[i * 1024 + idx];
        #pragma unroll
        for (int cc = 0; cc < 4; ++cc) {
            float4 v = qf4[(size_t)(c0 + cc) * 1024 + idx];
            #pragma unroll
            for (int i = 0; i < 10; ++i)
                acc[cc * 10 + i] += wv[i].x * v.x + wv[i].y * v.y + wv[i].z * v.z + wv[i].w * v.w;
        }
    }
    waveSum<40>(acc);
    if (lane == 63) {
        #pragma unroll
        for (int k = 0; k < 40; ++k) buf[wid * 40 + k] = acc[k];
    }
    __syncthreads();
    if (tid == 0) {
        float* ob = out + (size_t)b * 20 * NC;
        #pragma unroll
        for (int cc = 0; cc < 4; ++cc) {
            float s = 0.f;
            #pragma unroll
            for (int i = 0; i < 10; ++i) {
                float d = buf[cc * 10 + i] + buf[40 + cc * 10 + i]
                        + buf[80 + cc * 10 + i] + buf[120 + cc * 10 + i];
                float base = ob[i * NC + c0 + cc];
                float r = base + d;
                ob[(10 + i) * NC + c0 + cc] = r;
                s += base + r;
            }
            out[40960 + b * NC + c0 + cc] = s * 0.05f;
        }
    }
}

extern "C" void kernel_launch(void* const* d_in, const int* in_sizes, int n_in,
                              void* d_out, int out_size, void* d_ws, size_t ws_size,
                              hipStream_t stream) {
    const float* f1  = (const float*)d_in[0];
    const float* f2  = (const float*)d_in[1];
    const int*   m1  = (const int*)d_in[2];
    const int*   m2  = (const int*)d_in[3];
    const float* qf  = (const float*)d_in[4];
    const float* qp  = (const float*)d_in[5];
    const float* Wq  = (const float*)d_in[6];
    const float* Wk  = (const float*)d_in[7];
    const float* Wv  = (const float*)d_in[8];
    const float* tok = (const float*)d_in[9];
    float* out = (float*)d_out;
    float* ws  = (float*)d_ws;

    k_stage1<<<2304, 256, 0, stream>>>(f1, f2, m1, m2, Wq, Wk, ws);
    k_attnlogF<<<256, 256, 0, stream>>>(f1, f2, tok, ws);
    k_sinkhorn<<<16, 256, 0, stream>>>(m1, m2, ws);
    k_ps<<<4096, 256, 0, stream>>>(f1, f2, ws);
    k_outproto<<<256, 256, 0, stream>>>(Wv, tok, ws, out);
    k_attn2log<<<256, 256, 0, stream>>>(qf, out, ws);
    k_softmax2<<<80, 256, 0, stream>>>(qp, ws);
    k_apply2<<<512, 256, 0, stream>>>(qf, ws, out);
}

// Round 10
// 126.564 us; speedup vs baseline: 1.1929x; 1.1804x over previous
//
#include <hip/hip_runtime.h>
#include <hip/hip_bf16.h>
#include <math.h>

#define HW 4096
#define NC 256
#define NB 8
#define NA 5
#define NIT 24
#define SCL 0.0625f

// workspace layout (float offsets).
// Region A (655360 floats) reuse, in stream order:
//   1) k_attnlogF writes full L [sb16][a5][4096] (front 327680)
//   2) k_sinkhorn reads L, writes plan P [sb16][a5][4096] in place
//   3) k_ps consumes P; then k_attn2log writes logits [ig2][b8][ii5][4096]
// OFF_WQK aliases OFF_W2: Wqk lives there from k_stage1 until k_attnlogF
// reads it; k_softmax2 overwrites the region much later.
#define OFF_A     0
#define OFF_PROTO 655360                   // 2*8*256
#define OFF_PS    (OFF_PROTO + 4096 + 20480)
#define OFF_W2    (OFF_PS + 20480)         // 8*10*4096
#define OFF_WQK   OFF_W2                   // 256*256 alias (dead before softmax2)

__device__ inline float frcp(float x) { return __builtin_amdgcn_rcpf(x); }

// ---- DPP wave64 reductions: result valid in lane 63 ----
template<int NV>
__device__ inline void waveSum(float (&v)[NV]) {
    #pragma unroll
    for (int k = 0; k < NV; ++k) {
        float x = v[k]; int t;
        t = __builtin_amdgcn_update_dpp(0, __float_as_int(x), 0x111, 0xf, 0xf, true); x += __int_as_float(t);
        t = __builtin_amdgcn_update_dpp(0, __float_as_int(x), 0x112, 0xf, 0xf, true); x += __int_as_float(t);
        t = __builtin_amdgcn_update_dpp(0, __float_as_int(x), 0x114, 0xf, 0xf, true); x += __int_as_float(t);
        t = __builtin_amdgcn_update_dpp(0, __float_as_int(x), 0x118, 0xf, 0xf, true); x += __int_as_float(t);
        t = __builtin_amdgcn_update_dpp(0, __float_as_int(x), 0x142, 0xf, 0xf, true); x += __int_as_float(t);
        t = __builtin_amdgcn_update_dpp(0, __float_as_int(x), 0x143, 0xf, 0xf, true); x += __int_as_float(t);
        v[k] = x;
    }
}

template<int NV>
__device__ inline void waveMax(float (&v)[NV]) {
    #pragma unroll
    for (int k = 0; k < NV; ++k) {
        float x = v[k]; int t;
        t = __builtin_amdgcn_update_dpp(__float_as_int(x), __float_as_int(x), 0x111, 0xf, 0xf, false); x = fmaxf(x, __int_as_float(t));
        t = __builtin_amdgcn_update_dpp(__float_as_int(x), __float_as_int(x), 0x112, 0xf, 0xf, false); x = fmaxf(x, __int_as_float(t));
        t = __builtin_amdgcn_update_dpp(__float_as_int(x), __float_as_int(x), 0x114, 0xf, 0xf, false); x = fmaxf(x, __int_as_float(t));
        t = __builtin_amdgcn_update_dpp(__float_as_int(x), __float_as_int(x), 0x118, 0xf, 0xf, false); x = fmaxf(x, __int_as_float(t));
        t = __builtin_amdgcn_update_dpp(__float_as_int(x), __float_as_int(x), 0x142, 0xf, 0xf, false); x = fmaxf(x, __int_as_float(t));
        t = __builtin_amdgcn_update_dpp(__float_as_int(x), __float_as_int(x), 0x143, 0xf, 0xf, false); x = fmaxf(x, __int_as_float(t));
        v[k] = x;
    }
}

template<int NV>
__device__ inline void crossSum4(float (&v)[NV], float* buf, int lane, int wid) {
    waveSum<NV>(v);
    if (lane == 63) {
        #pragma unroll
        for (int k = 0; k < NV; ++k) buf[wid * NV + k] = v[k];
    }
    __syncthreads();
    #pragma unroll
    for (int k = 0; k < NV; ++k)
        v[k] = buf[k] + buf[NV + k] + buf[2 * NV + k] + buf[3 * NV + k];
}

template<int NV>
__device__ inline void crossMax4(float (&v)[NV], float* buf, int lane, int wid) {
    waveMax<NV>(v);
    if (lane == 63) {
        #pragma unroll
        for (int k = 0; k < NV; ++k) buf[wid * NV + k] = v[k];
    }
    __syncthreads();
    #pragma unroll
    for (int k = 0; k < NV; ++k)
        v[k] = fmaxf(fmaxf(buf[k], buf[NV + k]), fmaxf(buf[2 * NV + k], buf[3 * NV + k]));
}

// blocks 0..2047: proto for a PAIR of c rows (mask row read once per pair).
// blocks 2048..2303: Wqk = Wq^T @ Wk.
__global__ __launch_bounds__(256) void k_stage1(const float* __restrict__ f1, const float* __restrict__ f2,
                                                const int* __restrict__ m1, const int* __restrict__ m2,
                                                const float* __restrict__ Wq, const float* __restrict__ Wk,
                                                float* __restrict__ ws) {
    __shared__ float buf[12];
    int bid = blockIdx.x, tid = threadIdx.x;
    if (bid < 2048) {
        int lane = tid & 63, wid = tid >> 6;
        int s = bid >> 10, b = (bid >> 7) & 7, cp = bid & 127;
        int c0 = cp * 2;
        const float* f = s ? f2 : f1;
        const int* m = s ? m2 : m1;
        const float4* r0 = (const float4*)(f + ((size_t)b * NC + c0) * HW);
        const float4* r1 = (const float4*)(f + ((size_t)b * NC + c0 + 1) * HW);
        const int4* mb4 = (const int4*)(m + b * HW);
        float v3[3] = {0.f, 0.f, 0.f};   // sum_c0, sum_c1, count
        #pragma unroll
        for (int j = 0; j < 4; ++j) {
            int idx = tid + j * 256;
            float4 a = r0[idx];
            float4 c = r1[idx];
            int4 mm = mb4[idx];
            if (mm.x == 1) { v3[0] += a.x; v3[1] += c.x; v3[2] += 1.f; }
            if (mm.y == 1) { v3[0] += a.y; v3[1] += c.y; v3[2] += 1.f; }
            if (mm.z == 1) { v3[0] += a.z; v3[1] += c.z; v3[2] += 1.f; }
            if (mm.w == 1) { v3[0] += a.w; v3[1] += c.w; v3[2] += 1.f; }
        }
        crossSum4<3>(v3, buf, lane, wid);
        if (tid == 0) {
            float inv = 1.f / (v3[2] + 1e-5f);
            float* p = ws + OFF_PROTO + (s * 8 + b) * NC + c0;
            p[0] = v3[0] * inv;
            p[1] = v3[1] * inv;
        }
    } else {
        int c1 = bid - 2048;
        float acc = 0.f;
        #pragma unroll 8
        for (int cp = 0; cp < NC; ++cp)
            acc += Wq[(size_t)cp * NC + c1] * Wk[(size_t)cp * NC + tid];   // c1 uniform (s_load), tid coalesced
        ws[OFF_WQK + (size_t)c1 * NC + tid] = acc;
    }
}

// 1024 threads = 4 wave-groups; group g owns c-quarter [64g, 64g+64).
// phase A: qk[a][cout] quarter-parallel + in-block reduce.
// phase B: L[sb][a][n] quarter-partial + in-block reduce -> final L.
// grid = 16sb x 16nt = 256 blocks; thread owns 1 n (4 waves/SIMD resident).
__global__ __launch_bounds__(1024) void k_attnlogF(const float* __restrict__ f1, const float* __restrict__ f2,
                                                   const float* __restrict__ tok, float* __restrict__ ws) {
    __shared__ float sp3[NA * NC];
    __shared__ float qk_l[NA * NC];
    __shared__ float red[4 * NA * 256];
    int bid = blockIdx.x, tid = threadIdx.x;
    int nt = bid & 15, sb = bid >> 4;
    int s = sb >> 3, b = sb & 7;
    const float* f = s ? f2 : f1;
    const float* proto = ws + OFF_PROTO + sb * NC;
    for (int i = tid; i < NA * NC; i += 1024) sp3[i] = proto[i & 255] + tok[i];
    __syncthreads();
    int g = tid >> 8, t8 = tid & 255;
    {   // phase A: group g sums ci in its quarter for all couts
        const float* wq = ws + OFF_WQK + (size_t)(g * 64) * NC + t8;
        float a0 = 0, a1 = 0, a2 = 0, a3 = 0, a4 = 0;
        #pragma unroll 8
        for (int ci = 0; ci < 64; ++ci) {
            float w = wq[(size_t)ci * NC];
            int cix = g * 64 + ci;
            a0 += sp3[0 * NC + cix] * w; a1 += sp3[1 * NC + cix] * w; a2 += sp3[2 * NC + cix] * w;
            a3 += sp3[3 * NC + cix] * w; a4 += sp3[4 * NC + cix] * w;
        }
        red[(g * NA + 0) * 256 + t8] = a0; red[(g * NA + 1) * 256 + t8] = a1;
        red[(g * NA + 2) * 256 + t8] = a2; red[(g * NA + 3) * 256 + t8] = a3;
        red[(g * NA + 4) * 256 + t8] = a4;
    }
    __syncthreads();
    for (int o = tid; o < NA * 256; o += 1024) {
        int j = o >> 8, c = o & 255;
        qk_l[j * NC + c] = red[(0 * NA + j) * 256 + c] + red[(1 * NA + j) * 256 + c]
                         + red[(2 * NA + j) * 256 + c] + red[(3 * NA + j) * 256 + c];
    }
    __syncthreads();
    // phase B: group g handles c-quarter; thread owns n = nt*256 + t8
    int n = nt * 256 + t8;
    const float* fb = f + (size_t)b * NC * HW + n;
    {
        float acc[NA] = {};
        #pragma unroll 4
        for (int k = 0; k < 64; ++k) {
            int c = g * 64 + k;
            float v = fb[(size_t)c * HW];
            #pragma unroll
            for (int a = 0; a < NA; ++a) acc[a] += qk_l[a * NC + c] * v;
        }
        #pragma unroll
        for (int a = 0; a < NA; ++a) red[(g * NA + a) * 256 + t8] = acc[a];
    }
    __syncthreads();
    float* Lb = ws + OFF_A + (size_t)sb * NA * HW;
    for (int o = tid; o < NA * 256; o += 1024) {
        int j = o >> 8, c = o & 255;
        Lb[(size_t)j * HW + nt * 256 + c] =
            red[(0 * NA + j) * 256 + c] + red[(1 * NA + j) * 256 + c]
          + red[(2 * NA + j) * 256 + c] + red[(3 * NA + j) * 256 + c];
    }
}

// read L -> masked softmax -> K=exp(2*attn-2)*mask -> NIT iters -> plan P (in place)
__global__ __launch_bounds__(256) void k_sinkhorn(const int* __restrict__ m1, const int* __restrict__ m2,
                                                  float* __restrict__ ws) {
    __shared__ float buf[2][24];
    int sb = blockIdx.x, tid = threadIdx.x;
    int lane = tid & 63, wid = tid >> 6;
    int s = sb >> 3, b = sb & 7;
    const int* m = (s ? m2 : m1) + b * HW;
    const float4* A4 = (const float4*)(ws + OFF_A) + (size_t)sb * NA * 1024;
    const int4* mb4 = (const int4*)m;

    unsigned mbits = 0;
    float K[NA][16];
    #pragma unroll
    for (int j = 0; j < 4; ++j) {
        int idx = tid + j * 256;
        int4 mm = mb4[idx];
        if (mm.x == 1) mbits |= 1u << (4 * j + 0);
        if (mm.y == 1) mbits |= 1u << (4 * j + 1);
        if (mm.z == 1) mbits |= 1u << (4 * j + 2);
        if (mm.w == 1) mbits |= 1u << (4 * j + 3);
        #pragma unroll
        for (int a = 0; a < NA; ++a) {
            float4 l0 = A4[a * 1024 + idx];
            K[a][4 * j + 0] = l0.x; K[a][4 * j + 1] = l0.y;
            K[a][4 * j + 2] = l0.z; K[a][4 * j + 3] = l0.w;
        }
    }
    float r[NA];
    #pragma unroll
    for (int a = 0; a < NA; ++a) {
        float mx = -3.0e38f;
        #pragma unroll
        for (int j = 0; j < 16; ++j)
            if ((mbits >> j) & 1) mx = fmaxf(mx, K[a][j]);
        r[a] = mx;
    }
    crossMax4<NA>(r, buf[0], lane, wid);
    float rs6[6];
    #pragma unroll
    for (int a = 0; a < NA; ++a) {
        float sum = 0.f;
        #pragma unroll
        for (int j = 0; j < 16; ++j) {
            float e = ((mbits >> j) & 1) ? expf(K[a][j] - r[a]) : 0.f;
            K[a][j] = e; sum += e;
        }
        rs6[a] = sum;
    }
    rs6[5] = (float)__popc(mbits);
    crossSum4<6>(rs6, buf[1], lane, wid);
    float inv_cnt = frcp(rs6[5]);
    #pragma unroll
    for (int a = 0; a < NA; ++a) {
        float irs = frcp(rs6[a]);
        #pragma unroll
        for (int j = 0; j < 16; ++j) {
            float attn = K[a][j] * irs;
            K[a][j] = ((mbits >> j) & 1) ? expf(2.f * attn - 2.f) : 0.f;
        }
    }
    float u[NA];
    #pragma unroll
    for (int a = 0; a < NA; ++a) u[a] = 0.2f;
    for (int it = 0; it < NIT; ++it) {
        float part[NA] = {0, 0, 0, 0, 0};
        #pragma unroll
        for (int j = 0; j < 16; ++j) {
            float d = 0.f;
            #pragma unroll
            for (int a = 0; a < NA; ++a) d += K[a][j] * u[a];
            float t = inv_cnt * frcp(fmaxf(d, 1e-30f));
            #pragma unroll
            for (int a = 0; a < NA; ++a) part[a] += K[a][j] * t;
        }
        crossSum4<NA>(part, buf[it & 1], lane, wid);
        #pragma unroll
        for (int a = 0; a < NA; ++a) u[a] = 0.2f * frcp(fmaxf(part[a], 1e-30f));
    }
    float4* Pb4 = (float4*)(ws + OFF_A) + (size_t)sb * NA * 1024;   // overwrite own L
    #pragma unroll
    for (int j4 = 0; j4 < 4; ++j4) {
        int idx = tid + j4 * 256;
        float tcol[4];
        #pragma unroll
        for (int k = 0; k < 4; ++k) {
            int j = 4 * j4 + k;
            float d = 0.f;
            #pragma unroll
            for (int a = 0; a < NA; ++a) d += K[a][j] * u[a];
            tcol[k] = inv_cnt * frcp(fmaxf(d, 1e-30f));
        }
        #pragma unroll
        for (int a = 0; a < NA; ++a) {
            float4 o;
            o.x = u[a] * K[a][4 * j4 + 0] * tcol[0];
            o.y = u[a] * K[a][4 * j4 + 1] * tcol[1];
            o.z = u[a] * K[a][4 * j4 + 2] * tcol[2];
            o.w = u[a] * K[a][4 * j4 + 3] * tcol[3];
            Pb4[a * 1024 + idx] = o;
        }
    }
}

// ps[s][b][a][c] = sum_n P[a][n]*feat[c][n]
__global__ __launch_bounds__(256) void k_ps(const float* __restrict__ f1, const float* __restrict__ f2,
                                            float* __restrict__ ws) {
    __shared__ float buf[20];
    int bid = blockIdx.x, tid = threadIdx.x;
    int lane = tid & 63, wid = tid >> 6;
    int s = bid >> 11, b = (bid >> 8) & 7, c = bid & 255;
    const float* f = s ? f2 : f1;
    int sb = s * 8 + b;
    const float4* fb4 = (const float4*)(f + ((size_t)b * NC + c) * HW);
    const float4* Pb4 = (const float4*)(ws + OFF_A) + (size_t)sb * NA * 1024;
    float acc[NA] = {0, 0, 0, 0, 0};
    #pragma unroll
    for (int j = 0; j < 4; ++j) {
        int idx = tid + j * 256;
        float4 v = fb4[idx];
        #pragma unroll
        for (int a = 0; a < NA; ++a) {
            float4 p = Pb4[a * 1024 + idx];
            acc[a] += p.x * v.x + p.y * v.y + p.z * v.z + p.w * v.w;
        }
    }
    crossSum4<NA>(acc, buf, lane, wid);
    if (tid == 0) {
        float* ps = ws + OFF_PS + sb * NA * NC;
        #pragma unroll
        for (int a = 0; a < NA; ++a) ps[a * NC + c] = acc[a];
    }
}

// mem rows 0..9: proto3 + ps @ Wv^T.  grid = 16sb x 16 cout-tiles = 256 blocks.
__global__ __launch_bounds__(256) void k_outproto(const float* __restrict__ Wv, const float* __restrict__ tok,
                                                  float* __restrict__ ws, float* __restrict__ out) {
    __shared__ float wv_l[16][NC + 1];   // +1 pad: kills 16-way bank conflict
    __shared__ float ps_l[NA * NC];
    __shared__ float part[80][2];
    int bid = blockIdx.x, tid = threadIdx.x;
    int ctile = bid & 15, sb = bid >> 4;
    int s = sb >> 3, b = sb & 7;
    int c0 = ctile * 16;
    const float4* wv4 = (const float4*)(Wv + (size_t)c0 * NC);
    for (int t = tid; t < 1024; t += 256) {
        int r = t >> 6, q = t & 63;
        float4 v = wv4[(size_t)r * 64 + q];
        wv_l[r][4 * q + 0] = v.x; wv_l[r][4 * q + 1] = v.y;
        wv_l[r][4 * q + 2] = v.z; wv_l[r][4 * q + 3] = v.w;
    }
    const float* ps = ws + OFF_PS + sb * NA * NC;
    for (int i = tid; i < NA * NC; i += 256) ps_l[i] = ps[i];
    __syncthreads();
    if (tid < 160) {
        int o = tid >> 1, seg = tid & 1;
        int a = o >> 4, r = o & 15;
        const float* pa = ps_l + a * NC + seg * 128;
        const float* wr = &wv_l[r][seg * 128];
        float d = 0.f;
        #pragma unroll 8
        for (int i = 0; i < 128; ++i) d += pa[i] * wr[i];
        part[o][seg] = d;
    }
    __syncthreads();
    if (tid < 80) {
        int a = tid >> 4, r = tid & 15;
        int c = c0 + r;
        out[(size_t)b * 20 * NC + (s * NA + a) * NC + c] =
            ws[OFF_PROTO + sb * NC + c] + tok[a * NC + c] + part[tid][0] + part[tid][1];
    }
}

// attn2 logits (pre-softmax): w2log[ig][b][ii][n] = sum_c curr[ig*5+ii][c]*qf[c][n]
// 1024 threads = 4 c-quarter groups, in-block reduce -> final logits.
// grid = 8b x 16nt x 2ig = 256 blocks; thread owns 1 n.
__global__ __launch_bounds__(1024) void k_attn2log(const float* __restrict__ qf, const float* __restrict__ out,
                                                   float* __restrict__ ws) {
    __shared__ float sc_l[NA * NC];
    __shared__ float red[4 * NA * 256];
    int bid = blockIdx.x, tid = threadIdx.x;
    int ig = bid & 1, nt = (bid >> 1) & 15, b = bid >> 5;
    const float* cb = out + (size_t)b * 20 * NC + ig * NA * NC;
    for (int i = tid; i < NA * NC; i += 1024) sc_l[i] = cb[i];
    __syncthreads();
    int g = tid >> 8, t8 = tid & 255;
    int n = nt * 256 + t8;
    const float* fb = qf + (size_t)b * NC * HW + n;
    {
        float acc[NA] = {};
        #pragma unroll 4
        for (int k = 0; k < 64; ++k) {
            int c = g * 64 + k;
            float v = fb[(size_t)c * HW];
            #pragma unroll
            for (int a = 0; a < NA; ++a) acc[a] += sc_l[a * NC + c] * v;
        }
        #pragma unroll
        for (int a = 0; a < NA; ++a) red[(g * NA + a) * 256 + t8] = acc[a];
    }
    __syncthreads();
    float* pp = ws + OFF_A + (size_t)((ig * 8 + b) * NA) * HW;
    for (int o = tid; o < NA * 256; o += 1024) {
        int j = o >> 8, c = o & 255;
        pp[(size_t)j * HW + nt * 256 + c] =
            red[(0 * NA + j) * 256 + c] + red[(1 * NA + j) * 256 + c]
          + red[(2 * NA + j) * 256 + c] + red[(3 * NA + j) * 256 + c];
    }
}

// fg from qp inline, *SCL*fg, softmax, store attn*fg (single logit buffer now)
__global__ __launch_bounds__(256) void k_softmax2(const float* __restrict__ qp, float* __restrict__ ws) {
    __shared__ float buf[2][8];
    int row = blockIdx.x, tid = threadIdx.x;
    int lane = tid & 63, wid = tid >> 6;
    int b = row / 10, i = row - b * 10;
    int ig = i / NA, ii = i - ig * NA;
    const float4* pA = (const float4*)(ws + OFF_A) + (size_t)((ig * 8 + b) * NA + ii) * 1024;
    const float4* qp0 = (const float4*)(qp + (size_t)b * 2 * HW);
    const float4* qp1 = qp0 + 1024;
    float4 lg[4], fgv[4];
    float mx[1] = {-3.0e38f};
    #pragma unroll
    for (int j = 0; j < 4; ++j) {
        int idx = tid + j * 256;
        float4 a = pA[idx];
        float4 p0 = qp0[idx], p1 = qp1[idx];
        float4 fg;
        fg.x = 1.f / (1.f + expf(p0.x - p1.x));
        fg.y = 1.f / (1.f + expf(p0.y - p1.y));
        fg.z = 1.f / (1.f + expf(p0.z - p1.z));
        fg.w = 1.f / (1.f + expf(p0.w - p1.w));
        fg.x = fg.x > 0.7f ? 1.f : (fg.x < 0.3f ? 0.f : fg.x);
        fg.y = fg.y > 0.7f ? 1.f : (fg.y < 0.3f ? 0.f : fg.y);
        fg.z = fg.z > 0.7f ? 1.f : (fg.z < 0.3f ? 0.f : fg.z);
        fg.w = fg.w > 0.7f ? 1.f : (fg.w < 0.3f ? 0.f : fg.w);
        fgv[j] = fg;
        lg[j].x = a.x * SCL * fg.x;
        lg[j].y = a.y * SCL * fg.y;
        lg[j].z = a.z * SCL * fg.z;
        lg[j].w = a.w * SCL * fg.w;
        mx[0] = fmaxf(mx[0], fmaxf(fmaxf(lg[j].x, lg[j].y), fmaxf(lg[j].z, lg[j].w)));
    }
    crossMax4<1>(mx, buf[0], lane, wid);
    float sum[1] = {0.f};
    #pragma unroll
    for (int j = 0; j < 4; ++j) {
        lg[j].x = expf(lg[j].x - mx[0]); lg[j].y = expf(lg[j].y - mx[0]);
        lg[j].z = expf(lg[j].z - mx[0]); lg[j].w = expf(lg[j].w - mx[0]);
        sum[0] += lg[j].x + lg[j].y + lg[j].z + lg[j].w;
    }
    crossSum4<1>(sum, buf[1], lane, wid);
    float inv = frcp(sum[0]);
    float4* w24 = (float4*)(ws + OFF_W2) + (size_t)row * 1024;
    #pragma unroll
    for (int j = 0; j < 4; ++j) {
        int idx = tid + j * 256;
        float4 o;
        o.x = lg[j].x * inv * fgv[j].x;
        o.y = lg[j].y * inv * fgv[j].y;
        o.z = lg[j].z * inv * fgv[j].z;
        o.w = lg[j].w * inv * fgv[j].w;
        w24[idx] = o;
    }
}

// mem rows 10..19 = rows 0..9 + attn@qfm ; fused curr_prototype mean.
// grid = 8b x 64 column-groups (4 c each); all reg-array indexing static.
__global__ __launch_bounds__(256) void k_apply2(const float* __restrict__ qf, float* __restrict__ ws,
                                                float* __restrict__ out) {
    __shared__ float buf[4 * 40];
    int bid = blockIdx.x, tid = threadIdx.x;
    int lane = tid & 63, wid = tid >> 6;
    int b = bid >> 6, cg = bid & 63;
    int c0 = cg * 4;
    const float4* qf4 = (const float4*)(qf + (size_t)b * NC * HW);
    const float4* w24 = (const float4*)(ws + OFF_W2) + (size_t)b * 10 * 1024;
    float acc[40] = {};
    #pragma unroll
    for (int j = 0; j < 4; ++j) {
        int idx = tid + j * 256;
        float4 wv[10];
        #pragma unroll
        for (int i = 0; i < 10; ++i) wv[i] = w24[i * 1024 + idx];
        #pragma unroll
        for (int cc = 0; cc < 4; ++cc) {
            float4 v = qf4[(size_t)(c0 + cc) * 1024 + idx];
            #pragma unroll
            for (int i = 0; i < 10; ++i)
                acc[cc * 10 + i] += wv[i].x * v.x + wv[i].y * v.y + wv[i].z * v.z + wv[i].w * v.w;
        }
    }
    waveSum<40>(acc);
    if (lane == 63) {
        #pragma unroll
        for (int k = 0; k < 40; ++k) buf[wid * 40 + k] = acc[k];
    }
    __syncthreads();
    if (tid == 0) {
        float* ob = out + (size_t)b * 20 * NC;
        #pragma unroll
        for (int cc = 0; cc < 4; ++cc) {
            float s = 0.f;
            #pragma unroll
            for (int i = 0; i < 10; ++i) {
                float d = buf[cc * 10 + i] + buf[40 + cc * 10 + i]
                        + buf[80 + cc * 10 + i] + buf[120 + cc * 10 + i];
                float base = ob[i * NC + c0 + cc];
                float r = base + d;
                ob[(10 + i) * NC + c0 + cc] = r;
                s += base + r;
            }
            out[40960 + b * NC + c0 + cc] = s * 0.05f;
        }
    }
}

extern "C" void kernel_launch(void* const* d_in, const int* in_sizes, int n_in,
                              void* d_out, int out_size, void* d_ws, size_t ws_size,
                              hipStream_t stream) {
    const float* f1  = (const float*)d_in[0];
    const float* f2  = (const float*)d_in[1];
    const int*   m1  = (const int*)d_in[2];
    const int*   m2  = (const int*)d_in[3];
    const float* qf  = (const float*)d_in[4];
    const float* qp  = (const float*)d_in[5];
    const float* Wq  = (const float*)d_in[6];
    const float* Wk  = (const float*)d_in[7];
    const float* Wv  = (const float*)d_in[8];
    const float* tok = (const float*)d_in[9];
    float* out = (float*)d_out;
    float* ws  = (float*)d_ws;

    k_stage1<<<2304, 256, 0, stream>>>(f1, f2, m1, m2, Wq, Wk, ws);
    k_attnlogF<<<256, 1024, 0, stream>>>(f1, f2, tok, ws);
    k_sinkhorn<<<16, 256, 0, stream>>>(m1, m2, ws);
    k_ps<<<4096, 256, 0, stream>>>(f1, f2, ws);
    k_outproto<<<256, 256, 0, stream>>>(Wv, tok, ws, out);
    k_attn2log<<<256, 1024, 0, stream>>>(qf, out, ws);
    k_softmax2<<<80, 256, 0, stream>>>(qp, ws);
    k_apply2<<<512, 256, 0, stream>>>(qf, ws, out);
}

// Round 11
// 120.446 us; speedup vs baseline: 1.2535x; 1.0508x over previous
//
#include <hip/hip_runtime.h>
#include <hip/hip_bf16.h>
#include <math.h>

#define HW 4096
#define NC 256
#define NB 8
#define NA 5
#define NIT 24
#define SCL 0.0625f

// workspace layout (float offsets).
// Region A (655360 floats) reuse, in stream order:
//   1) k_attnlogF writes full L [sb16][a5][4096] (front 327680)
//   2) k_sinkhorn reads L, writes plan P [sb16][a5][4096] in place
//   3) k_ps consumes P; then k_attn2log writes logits [ig2][b8][ii5][4096]
// OFF_WQK aliases OFF_W2: Wqk lives there from k_stage1 until k_attnlogF
// reads it; k_softmax2 overwrites the region much later.
#define OFF_A     0
#define OFF_PROTO 655360                   // 2*8*256
#define OFF_PS    (OFF_PROTO + 4096 + 20480)
#define OFF_W2    (OFF_PS + 20480)         // 8*10*4096
#define OFF_WQK   OFF_W2                   // 256*256 alias (dead before softmax2)

__device__ inline float frcp(float x) { return __builtin_amdgcn_rcpf(x); }

// ---- DPP wave64 reductions: result valid in lane 63 ----
template<int NV>
__device__ inline void waveSum(float (&v)[NV]) {
    #pragma unroll
    for (int k = 0; k < NV; ++k) {
        float x = v[k]; int t;
        t = __builtin_amdgcn_update_dpp(0, __float_as_int(x), 0x111, 0xf, 0xf, true); x += __int_as_float(t);
        t = __builtin_amdgcn_update_dpp(0, __float_as_int(x), 0x112, 0xf, 0xf, true); x += __int_as_float(t);
        t = __builtin_amdgcn_update_dpp(0, __float_as_int(x), 0x114, 0xf, 0xf, true); x += __int_as_float(t);
        t = __builtin_amdgcn_update_dpp(0, __float_as_int(x), 0x118, 0xf, 0xf, true); x += __int_as_float(t);
        t = __builtin_amdgcn_update_dpp(0, __float_as_int(x), 0x142, 0xf, 0xf, true); x += __int_as_float(t);
        t = __builtin_amdgcn_update_dpp(0, __float_as_int(x), 0x143, 0xf, 0xf, true); x += __int_as_float(t);
        v[k] = x;
    }
}

template<int NV>
__device__ inline void waveMax(float (&v)[NV]) {
    #pragma unroll
    for (int k = 0; k < NV; ++k) {
        float x = v[k]; int t;
        t = __builtin_amdgcn_update_dpp(__float_as_int(x), __float_as_int(x), 0x111, 0xf, 0xf, false); x = fmaxf(x, __int_as_float(t));
        t = __builtin_amdgcn_update_dpp(__float_as_int(x), __float_as_int(x), 0x112, 0xf, 0xf, false); x = fmaxf(x, __int_as_float(t));
        t = __builtin_amdgcn_update_dpp(__float_as_int(x), __float_as_int(x), 0x114, 0xf, 0xf, false); x = fmaxf(x, __int_as_float(t));
        t = __builtin_amdgcn_update_dpp(__float_as_int(x), __float_as_int(x), 0x118, 0xf, 0xf, false); x = fmaxf(x, __int_as_float(t));
        t = __builtin_amdgcn_update_dpp(__float_as_int(x), __float_as_int(x), 0x142, 0xf, 0xf, false); x = fmaxf(x, __int_as_float(t));
        t = __builtin_amdgcn_update_dpp(__float_as_int(x), __float_as_int(x), 0x143, 0xf, 0xf, false); x = fmaxf(x, __int_as_float(t));
        v[k] = x;
    }
}

template<int NV>
__device__ inline void crossSum4(float (&v)[NV], float* buf, int lane, int wid) {
    waveSum<NV>(v);
    if (lane == 63) {
        #pragma unroll
        for (int k = 0; k < NV; ++k) buf[wid * NV + k] = v[k];
    }
    __syncthreads();
    #pragma unroll
    for (int k = 0; k < NV; ++k)
        v[k] = buf[k] + buf[NV + k] + buf[2 * NV + k] + buf[3 * NV + k];
}

template<int NV>
__device__ inline void crossMax4(float (&v)[NV], float* buf, int lane, int wid) {
    waveMax<NV>(v);
    if (lane == 63) {
        #pragma unroll
        for (int k = 0; k < NV; ++k) buf[wid * NV + k] = v[k];
    }
    __syncthreads();
    #pragma unroll
    for (int k = 0; k < NV; ++k)
        v[k] = fmaxf(fmaxf(buf[k], buf[NV + k]), fmaxf(buf[2 * NV + k], buf[3 * NV + k]));
}

// blocks 0..1023: proto for a QUAD of c rows (mask row read once per quad).
// blocks 1024..1279: Wqk = Wq^T @ Wk.
__global__ __launch_bounds__(256) void k_stage1(const float* __restrict__ f1, const float* __restrict__ f2,
                                                const int* __restrict__ m1, const int* __restrict__ m2,
                                                const float* __restrict__ Wq, const float* __restrict__ Wk,
                                                float* __restrict__ ws) {
    __shared__ float buf[20];
    int bid = blockIdx.x, tid = threadIdx.x;
    if (bid < 1024) {
        int lane = tid & 63, wid = tid >> 6;
        int s = bid >> 9, b = (bid >> 6) & 7, cq = bid & 63;
        int c0 = cq * 4;
        const float* f = s ? f2 : f1;
        const int* m = s ? m2 : m1;
        const float4* r0 = (const float4*)(f + ((size_t)b * NC + c0 + 0) * HW);
        const float4* r1 = (const float4*)(f + ((size_t)b * NC + c0 + 1) * HW);
        const float4* r2 = (const float4*)(f + ((size_t)b * NC + c0 + 2) * HW);
        const float4* r3 = (const float4*)(f + ((size_t)b * NC + c0 + 3) * HW);
        const int4* mb4 = (const int4*)(m + b * HW);
        float v5[5] = {0.f, 0.f, 0.f, 0.f, 0.f};   // sums c0..c3, count
        #pragma unroll
        for (int j = 0; j < 4; ++j) {
            int idx = tid + j * 256;
            float4 a = r0[idx], c = r1[idx], d = r2[idx], e = r3[idx];
            int4 mm = mb4[idx];
            if (mm.x == 1) { v5[0] += a.x; v5[1] += c.x; v5[2] += d.x; v5[3] += e.x; v5[4] += 1.f; }
            if (mm.y == 1) { v5[0] += a.y; v5[1] += c.y; v5[2] += d.y; v5[3] += e.y; v5[4] += 1.f; }
            if (mm.z == 1) { v5[0] += a.z; v5[1] += c.z; v5[2] += d.z; v5[3] += e.z; v5[4] += 1.f; }
            if (mm.w == 1) { v5[0] += a.w; v5[1] += c.w; v5[2] += d.w; v5[3] += e.w; v5[4] += 1.f; }
        }
        crossSum4<5>(v5, buf, lane, wid);
        if (tid == 0) {
            float inv = 1.f / (v5[4] + 1e-5f);
            float* p = ws + OFF_PROTO + (s * 8 + b) * NC + c0;
            p[0] = v5[0] * inv; p[1] = v5[1] * inv;
            p[2] = v5[2] * inv; p[3] = v5[3] * inv;
        }
    } else {
        int c1 = bid - 1024;
        float acc = 0.f;
        #pragma unroll 8
        for (int cp = 0; cp < NC; ++cp)
            acc += Wq[(size_t)cp * NC + c1] * Wk[(size_t)cp * NC + tid];   // c1 uniform (s_load), tid coalesced
        ws[OFF_WQK + (size_t)c1 * NC + tid] = acc;
    }
}

// 1024 threads = 4 wave-groups; group g owns c-quarter [64g, 64g+64).
// phase A: qk[a][cout] quarter-parallel + in-block reduce.
// phase B: L[sb][a][n] quarter-partial + in-block reduce -> final L.
// grid = 16sb x 16nt = 256 blocks; thread owns 1 n (4 waves/SIMD resident).
__global__ __launch_bounds__(1024) void k_attnlogF(const float* __restrict__ f1, const float* __restrict__ f2,
                                                   const float* __restrict__ tok, float* __restrict__ ws) {
    __shared__ float sp3[NA * NC];
    __shared__ float qk_l[NA * NC];
    __shared__ float red[4 * NA * 256];
    int bid = blockIdx.x, tid = threadIdx.x;
    int nt = bid & 15, sb = bid >> 4;
    int s = sb >> 3, b = sb & 7;
    const float* f = s ? f2 : f1;
    const float* proto = ws + OFF_PROTO + sb * NC;
    for (int i = tid; i < NA * NC; i += 1024) sp3[i] = proto[i & 255] + tok[i];
    __syncthreads();
    int g = tid >> 8, t8 = tid & 255;
    {   // phase A: group g sums ci in its quarter for all couts
        const float* wq = ws + OFF_WQK + (size_t)(g * 64) * NC + t8;
        float a0 = 0, a1 = 0, a2 = 0, a3 = 0, a4 = 0;
        #pragma unroll 8
        for (int ci = 0; ci < 64; ++ci) {
            float w = wq[(size_t)ci * NC];
            int cix = g * 64 + ci;
            a0 += sp3[0 * NC + cix] * w; a1 += sp3[1 * NC + cix] * w; a2 += sp3[2 * NC + cix] * w;
            a3 += sp3[3 * NC + cix] * w; a4 += sp3[4 * NC + cix] * w;
        }
        red[(g * NA + 0) * 256 + t8] = a0; red[(g * NA + 1) * 256 + t8] = a1;
        red[(g * NA + 2) * 256 + t8] = a2; red[(g * NA + 3) * 256 + t8] = a3;
        red[(g * NA + 4) * 256 + t8] = a4;
    }
    __syncthreads();
    for (int o = tid; o < NA * 256; o += 1024) {
        int j = o >> 8, c = o & 255;
        qk_l[j * NC + c] = red[(0 * NA + j) * 256 + c] + red[(1 * NA + j) * 256 + c]
                         + red[(2 * NA + j) * 256 + c] + red[(3 * NA + j) * 256 + c];
    }
    __syncthreads();
    // phase B: group g handles c-quarter; thread owns n = nt*256 + t8
    int n = nt * 256 + t8;
    const float* fb = f + (size_t)b * NC * HW + n;
    {
        float acc[NA] = {};
        #pragma unroll 4
        for (int k = 0; k < 64; ++k) {
            int c = g * 64 + k;
            float v = fb[(size_t)c * HW];
            #pragma unroll
            for (int a = 0; a < NA; ++a) acc[a] += qk_l[a * NC + c] * v;
        }
        #pragma unroll
        for (int a = 0; a < NA; ++a) red[(g * NA + a) * 256 + t8] = acc[a];
    }
    __syncthreads();
    float* Lb = ws + OFF_A + (size_t)sb * NA * HW;
    for (int o = tid; o < NA * 256; o += 1024) {
        int j = o >> 8, c = o & 255;
        Lb[(size_t)j * HW + nt * 256 + c] =
            red[(0 * NA + j) * 256 + c] + red[(1 * NA + j) * 256 + c]
          + red[(2 * NA + j) * 256 + c] + red[(3 * NA + j) * 256 + c];
    }
}

// read L -> masked softmax -> K=exp(2*attn-2)*mask -> NIT iters -> plan P (in place)
__global__ __launch_bounds__(256) void k_sinkhorn(const int* __restrict__ m1, const int* __restrict__ m2,
                                                  float* __restrict__ ws) {
    __shared__ float buf[2][24];
    int sb = blockIdx.x, tid = threadIdx.x;
    int lane = tid & 63, wid = tid >> 6;
    int s = sb >> 3, b = sb & 7;
    const int* m = (s ? m2 : m1) + b * HW;
    const float4* A4 = (const float4*)(ws + OFF_A) + (size_t)sb * NA * 1024;
    const int4* mb4 = (const int4*)m;

    unsigned mbits = 0;
    float K[NA][16];
    #pragma unroll
    for (int j = 0; j < 4; ++j) {
        int idx = tid + j * 256;
        int4 mm = mb4[idx];
        if (mm.x == 1) mbits |= 1u << (4 * j + 0);
        if (mm.y == 1) mbits |= 1u << (4 * j + 1);
        if (mm.z == 1) mbits |= 1u << (4 * j + 2);
        if (mm.w == 1) mbits |= 1u << (4 * j + 3);
        #pragma unroll
        for (int a = 0; a < NA; ++a) {
            float4 l0 = A4[a * 1024 + idx];
            K[a][4 * j + 0] = l0.x; K[a][4 * j + 1] = l0.y;
            K[a][4 * j + 2] = l0.z; K[a][4 * j + 3] = l0.w;
        }
    }
    float r[NA];
    #pragma unroll
    for (int a = 0; a < NA; ++a) {
        float mx = -3.0e38f;
        #pragma unroll
        for (int j = 0; j < 16; ++j)
            if ((mbits >> j) & 1) mx = fmaxf(mx, K[a][j]);
        r[a] = mx;
    }
    crossMax4<NA>(r, buf[0], lane, wid);
    float rs6[6];
    #pragma unroll
    for (int a = 0; a < NA; ++a) {
        float sum = 0.f;
        #pragma unroll
        for (int j = 0; j < 16; ++j) {
            float e = ((mbits >> j) & 1) ? expf(K[a][j] - r[a]) : 0.f;
            K[a][j] = e; sum += e;
        }
        rs6[a] = sum;
    }
    rs6[5] = (float)__popc(mbits);
    crossSum4<6>(rs6, buf[1], lane, wid);
    float inv_cnt = frcp(rs6[5]);
    #pragma unroll
    for (int a = 0; a < NA; ++a) {
        float irs = frcp(rs6[a]);
        #pragma unroll
        for (int j = 0; j < 16; ++j) {
            float attn = K[a][j] * irs;
            K[a][j] = ((mbits >> j) & 1) ? expf(2.f * attn - 2.f) : 0.f;
        }
    }
    float u[NA];
    #pragma unroll
    for (int a = 0; a < NA; ++a) u[a] = 0.2f;
    for (int it = 0; it < NIT; ++it) {
        float part[NA] = {0, 0, 0, 0, 0};
        #pragma unroll
        for (int j = 0; j < 16; ++j) {
            float d = 0.f;
            #pragma unroll
            for (int a = 0; a < NA; ++a) d += K[a][j] * u[a];
            float t = inv_cnt * frcp(fmaxf(d, 1e-30f));
            #pragma unroll
            for (int a = 0; a < NA; ++a) part[a] += K[a][j] * t;
        }
        crossSum4<NA>(part, buf[it & 1], lane, wid);
        #pragma unroll
        for (int a = 0; a < NA; ++a) u[a] = 0.2f * frcp(fmaxf(part[a], 1e-30f));
    }
    float4* Pb4 = (float4*)(ws + OFF_A) + (size_t)sb * NA * 1024;   // overwrite own L
    #pragma unroll
    for (int j4 = 0; j4 < 4; ++j4) {
        int idx = tid + j4 * 256;
        float tcol[4];
        #pragma unroll
        for (int k = 0; k < 4; ++k) {
            int j = 4 * j4 + k;
            float d = 0.f;
            #pragma unroll
            for (int a = 0; a < NA; ++a) d += K[a][j] * u[a];
            tcol[k] = inv_cnt * frcp(fmaxf(d, 1e-30f));
        }
        #pragma unroll
        for (int a = 0; a < NA; ++a) {
            float4 o;
            o.x = u[a] * K[a][4 * j4 + 0] * tcol[0];
            o.y = u[a] * K[a][4 * j4 + 1] * tcol[1];
            o.z = u[a] * K[a][4 * j4 + 2] * tcol[2];
            o.w = u[a] * K[a][4 * j4 + 3] * tcol[3];
            Pb4[a * 1024 + idx] = o;
        }
    }
}

// ps[s][b][a][c] for a PAIR of c rows: sum_n P[a][n]*feat[c][n]
// grid = 2s x 8b x 128 cpair = 2048 blocks.
__global__ __launch_bounds__(256) void k_ps(const float* __restrict__ f1, const float* __restrict__ f2,
                                            float* __restrict__ ws) {
    __shared__ float buf[40];
    int bid = blockIdx.x, tid = threadIdx.x;
    int lane = tid & 63, wid = tid >> 6;
    int s = bid >> 10, b = (bid >> 7) & 7, cp = bid & 127;
    int c0 = cp * 2;
    const float* f = s ? f2 : f1;
    int sb = s * 8 + b;
    const float4* r0 = (const float4*)(f + ((size_t)b * NC + c0 + 0) * HW);
    const float4* r1 = (const float4*)(f + ((size_t)b * NC + c0 + 1) * HW);
    const float4* Pb4 = (const float4*)(ws + OFF_A) + (size_t)sb * NA * 1024;
    float acc[10] = {};
    #pragma unroll
    for (int j = 0; j < 4; ++j) {
        int idx = tid + j * 256;
        float4 v0 = r0[idx], v1 = r1[idx];
        #pragma unroll
        for (int a = 0; a < NA; ++a) {
            float4 p = Pb4[a * 1024 + idx];
            acc[a]      += p.x * v0.x + p.y * v0.y + p.z * v0.z + p.w * v0.w;
            acc[NA + a] += p.x * v1.x + p.y * v1.y + p.z * v1.z + p.w * v1.w;
        }
    }
    crossSum4<10>(acc, buf, lane, wid);
    if (tid == 0) {
        float* ps = ws + OFF_PS + sb * NA * NC;
        #pragma unroll
        for (int a = 0; a < NA; ++a) {
            ps[a * NC + c0 + 0] = acc[a];
            ps[a * NC + c0 + 1] = acc[NA + a];
        }
    }
}

// mem rows 0..9: proto3 + ps @ Wv^T.  grid = 16sb x 16 cout-tiles = 256 blocks.
__global__ __launch_bounds__(256) void k_outproto(const float* __restrict__ Wv, const float* __restrict__ tok,
                                                  float* __restrict__ ws, float* __restrict__ out) {
    __shared__ float wv_l[16][NC + 1];   // +1 pad: kills 16-way bank conflict
    __shared__ float ps_l[NA * NC];
    __shared__ float part[80][2];
    int bid = blockIdx.x, tid = threadIdx.x;
    int ctile = bid & 15, sb = bid >> 4;
    int s = sb >> 3, b = sb & 7;
    int c0 = ctile * 16;
    const float4* wv4 = (const float4*)(Wv + (size_t)c0 * NC);
    for (int t = tid; t < 1024; t += 256) {
        int r = t >> 6, q = t & 63;
        float4 v = wv4[(size_t)r * 64 + q];
        wv_l[r][4 * q + 0] = v.x; wv_l[r][4 * q + 1] = v.y;
        wv_l[r][4 * q + 2] = v.z; wv_l[r][4 * q + 3] = v.w;
    }
    const float* ps = ws + OFF_PS + sb * NA * NC;
    for (int i = tid; i < NA * NC; i += 256) ps_l[i] = ps[i];
    __syncthreads();
    if (tid < 160) {
        int o = tid >> 1, seg = tid & 1;
        int a = o >> 4, r = o & 15;
        const float* pa = ps_l + a * NC + seg * 128;
        const float* wr = &wv_l[r][seg * 128];
        float d = 0.f;
        #pragma unroll 8
        for (int i = 0; i < 128; ++i) d += pa[i] * wr[i];
        part[o][seg] = d;
    }
    __syncthreads();
    if (tid < 80) {
        int a = tid >> 4, r = tid & 15;
        int c = c0 + r;
        out[(size_t)b * 20 * NC + (s * NA + a) * NC + c] =
            ws[OFF_PROTO + sb * NC + c] + tok[a * NC + c] + part[tid][0] + part[tid][1];
    }
}

// attn2 logits (pre-softmax): w2log[ig][b][ii][n] = sum_c curr[ig*5+ii][c]*qf[c][n]
// 1024 threads = 4 c-quarter groups, in-block reduce -> final logits.
// grid = 8b x 16nt x 2ig = 256 blocks; thread owns 1 n.
__global__ __launch_bounds__(1024) void k_attn2log(const float* __restrict__ qf, const float* __restrict__ out,
                                                   float* __restrict__ ws) {
    __shared__ float sc_l[NA * NC];
    __shared__ float red[4 * NA * 256];
    int bid = blockIdx.x, tid = threadIdx.x;
    int ig = bid & 1, nt = (bid >> 1) & 15, b = bid >> 5;
    const float* cb = out + (size_t)b * 20 * NC + ig * NA * NC;
    for (int i = tid; i < NA * NC; i += 1024) sc_l[i] = cb[i];
    __syncthreads();
    int g = tid >> 8, t8 = tid & 255;
    int n = nt * 256 + t8;
    const float* fb = qf + (size_t)b * NC * HW + n;
    {
        float acc[NA] = {};
        #pragma unroll 4
        for (int k = 0; k < 64; ++k) {
            int c = g * 64 + k;
            float v = fb[(size_t)c * HW];
            #pragma unroll
            for (int a = 0; a < NA; ++a) acc[a] += sc_l[a * NC + c] * v;
        }
        #pragma unroll
        for (int a = 0; a < NA; ++a) red[(g * NA + a) * 256 + t8] = acc[a];
    }
    __syncthreads();
    float* pp = ws + OFF_A + (size_t)((ig * 8 + b) * NA) * HW;
    for (int o = tid; o < NA * 256; o += 1024) {
        int j = o >> 8, c = o & 255;
        pp[(size_t)j * HW + nt * 256 + c] =
            red[(0 * NA + j) * 256 + c] + red[(1 * NA + j) * 256 + c]
          + red[(2 * NA + j) * 256 + c] + red[(3 * NA + j) * 256 + c];
    }
}

// fg from qp inline, *SCL*fg, softmax, store attn*fg (single logit buffer now)
__global__ __launch_bounds__(256) void k_softmax2(const float* __restrict__ qp, float* __restrict__ ws) {
    __shared__ float buf[2][8];
    int row = blockIdx.x, tid = threadIdx.x;
    int lane = tid & 63, wid = tid >> 6;
    int b = row / 10, i = row - b * 10;
    int ig = i / NA, ii = i - ig * NA;
    const float4* pA = (const float4*)(ws + OFF_A) + (size_t)((ig * 8 + b) * NA + ii) * 1024;
    const float4* qp0 = (const float4*)(qp + (size_t)b * 2 * HW);
    const float4* qp1 = qp0 + 1024;
    float4 lg[4], fgv[4];
    float mx[1] = {-3.0e38f};
    #pragma unroll
    for (int j = 0; j < 4; ++j) {
        int idx = tid + j * 256;
        float4 a = pA[idx];
        float4 p0 = qp0[idx], p1 = qp1[idx];
        float4 fg;
        fg.x = 1.f / (1.f + expf(p0.x - p1.x));
        fg.y = 1.f / (1.f + expf(p0.y - p1.y));
        fg.z = 1.f / (1.f + expf(p0.z - p1.z));
        fg.w = 1.f / (1.f + expf(p0.w - p1.w));
        fg.x = fg.x > 0.7f ? 1.f : (fg.x < 0.3f ? 0.f : fg.x);
        fg.y = fg.y > 0.7f ? 1.f : (fg.y < 0.3f ? 0.f : fg.y);
        fg.z = fg.z > 0.7f ? 1.f : (fg.z < 0.3f ? 0.f : fg.z);
        fg.w = fg.w > 0.7f ? 1.f : (fg.w < 0.3f ? 0.f : fg.w);
        fgv[j] = fg;
        lg[j].x = a.x * SCL * fg.x;
        lg[j].y = a.y * SCL * fg.y;
        lg[j].z = a.z * SCL * fg.z;
        lg[j].w = a.w * SCL * fg.w;
        mx[0] = fmaxf(mx[0], fmaxf(fmaxf(lg[j].x, lg[j].y), fmaxf(lg[j].z, lg[j].w)));
    }
    crossMax4<1>(mx, buf[0], lane, wid);
    float sum[1] = {0.f};
    #pragma unroll
    for (int j = 0; j < 4; ++j) {
        lg[j].x = expf(lg[j].x - mx[0]); lg[j].y = expf(lg[j].y - mx[0]);
        lg[j].z = expf(lg[j].z - mx[0]); lg[j].w = expf(lg[j].w - mx[0]);
        sum[0] += lg[j].x + lg[j].y + lg[j].z + lg[j].w;
    }
    crossSum4<1>(sum, buf[1], lane, wid);
    float inv = frcp(sum[0]);
    float4* w24 = (float4*)(ws + OFF_W2) + (size_t)row * 1024;
    #pragma unroll
    for (int j = 0; j < 4; ++j) {
        int idx = tid + j * 256;
        float4 o;
        o.x = lg[j].x * inv * fgv[j].x;
        o.y = lg[j].y * inv * fgv[j].y;
        o.z = lg[j].z * inv * fgv[j].z;
        o.w = lg[j].w * inv * fgv[j].w;
        w24[idx] = o;
    }
}

// mem rows 10..19 = rows 0..9 + attn@qfm ; fused curr_prototype mean.
// grid = 8b x 64 column-groups (4 c each); all reg-array indexing static.
__global__ __launch_bounds__(256) void k_apply2(const float* __restrict__ qf, float* __restrict__ ws,
                                                float* __restrict__ out) {
    __shared__ float buf[4 * 40];
    int bid = blockIdx.x, tid = threadIdx.x;
    int lane = tid & 63, wid = tid >> 6;
    int b = bid >> 6, cg = bid & 63;
    int c0 = cg * 4;
    const float4* qf4 = (const float4*)(qf + (size_t)b * NC * HW);
    const float4* w24 = (const float4*)(ws + OFF_W2) + (size_t)b * 10 * 1024;
    float acc[40] = {};
    #pragma unroll
    for (int j = 0; j < 4; ++j) {
        int idx = tid + j * 256;
        float4 wv[10];
        #pragma unroll
        for (int i = 0; i < 10; ++i) wv[i] = w24[i * 1024 + idx];
        #pragma unroll
        for (int cc = 0; cc < 4; ++cc) {
            float4 v = qf4[(size_t)(c0 + cc) * 1024 + idx];
            #pragma unroll
            for (int i = 0; i < 10; ++i)
                acc[cc * 10 + i] += wv[i].x * v.x + wv[i].y * v.y + wv[i].z * v.z + wv[i].w * v.w;
        }
    }
    waveSum<40>(acc);
    if (lane == 63) {
        #pragma unroll
        for (int k = 0; k < 40; ++k) buf[wid * 40 + k] = acc[k];
    }
    __syncthreads();
    if (tid == 0) {
        float* ob = out + (size_t)b * 20 * NC;
        #pragma unroll
        for (int cc = 0; cc < 4; ++cc) {
            float s = 0.f;
            #pragma unroll
            for (int i = 0; i < 10; ++i) {
                float d = buf[cc * 10 + i] + buf[40 + cc * 10 + i]
                        + buf[80 + cc * 10 + i] + buf[120 + cc * 10 + i];
                float base = ob[i * NC + c0 + cc];
                float r = base + d;
                ob[(10 + i) * NC + c0 + cc] = r;
                s += base + r;
            }
            out[40960 + b * NC + c0 + cc] = s * 0.05f;
        }
    }
}

extern "C" void kernel_launch(void* const* d_in, const int* in_sizes, int n_in,
                              void* d_out, int out_size, void* d_ws, size_t ws_size,
                              hipStream_t stream) {
    const float* f1  = (const float*)d_in[0];
    const float* f2  = (const float*)d_in[1];
    const int*   m1  = (const int*)d_in[2];
    const int*   m2  = (const int*)d_in[3];
    const float* qf  = (const float*)d_in[4];
    const float* qp  = (const float*)d_in[5];
    const float* Wq  = (const float*)d_in[6];
    const float* Wk  = (const float*)d_in[7];
    const float* Wv  = (const float*)d_in[8];
    const float* tok = (const float*)d_in[9];
    float* out = (float*)d_out;
    float* ws  = (float*)d_ws;

    k_stage1<<<1280, 256, 0, stream>>>(f1, f2, m1, m2, Wq, Wk, ws);
    k_attnlogF<<<256, 1024, 0, stream>>>(f1, f2, tok, ws);
    k_sinkhorn<<<16, 256, 0, stream>>>(m1, m2, ws);
    k_ps<<<2048, 256, 0, stream>>>(f1, f2, ws);
    k_outproto<<<256, 256, 0, stream>>>(Wv, tok, ws, out);
    k_attn2log<<<256, 1024, 0, stream>>>(qf, out, ws);
    k_softmax2<<<80, 256, 0, stream>>>(qp, ws);
    k_apply2<<<512, 256, 0, stream>>>(qf, ws, out);
}